// Round 7
// baseline (279.674 us; speedup 1.0000x reference)
//
#include <hip/hip_runtime.h>
#include <math.h>

#define NB    8
#define CDIM  256
#define NN    2304
#define NH    4
#define DH    32
#define HIDC  128
#define OC3   384
#define SCALE_LOG2E 0.25503524964550864f         // 32^-0.5 * log2(e)
#define SEG   2359296                            // NB*NH*NN*DH
#define LSEG  73728                              // NB*NH*NN
#define PPARTS 4
#define JCHUNK 576                               // NN / PPARTS
#define NITER  18                                // JCHUNK / 32

typedef short  bf16x8 __attribute__((ext_vector_type(8)));
typedef short  bf16x4 __attribute__((ext_vector_type(4)));
typedef float  f32x4  __attribute__((ext_vector_type(4)));

__device__ __forceinline__ unsigned short f2bf(float f) {
    union { float f; unsigned u; } a; a.f = f;
    unsigned r = a.u + 0x7fffu + ((a.u >> 16) & 1u);   // RNE
    return (unsigned short)(r >> 16);
}

__device__ __forceinline__ unsigned pack_trunc(float lo, float hi) {
    union { float f; unsigned u; } a, b; a.f = lo; b.f = hi;
    return (b.u & 0xFFFF0000u) | (a.u >> 16);          // bf16x2, truncated
}

__device__ __forceinline__ float bflo(unsigned u) {
    union { unsigned u; float f; } c; c.u = u << 16; return c.f;
}
__device__ __forceinline__ float bfhi(unsigned u) {
    union { unsigned u; float f; } c; c.u = u & 0xFFFF0000u; return c.f;
}

__device__ __forceinline__ bf16x4 mk4(unsigned a, unsigned b) {
    union { unsigned u[2]; bf16x4 v; } t; t.u[0] = a; t.u[1] = b; return t.v;
}

// 16x16x16 bf16 MFMA: A-frag layout (m=lane&15, k=quad*4+r) == C/D layout of
// the 16x16x32 S-MFMA, so exp'd scores feed PV directly (no transpose).
__device__ __forceinline__ f32x4 mfma1616(bf16x4 a, bf16x4 b, f32x4 c) {
#if __has_builtin(__builtin_amdgcn_mfma_f32_16x16x16bf16_1k)
    return __builtin_amdgcn_mfma_f32_16x16x16bf16_1k(a, b, c, 0, 0, 0);
#else
    f32x4 d;
    asm volatile("v_mfma_f32_16x16x16_bf16 %0, %1, %2, %3\n\t"
                 "s_nop 7\n\ts_nop 7"
                 : "=v"(d) : "v"(a), "v"(b), "v"(c));
    return d;
#endif
}

// ---------------------------------------------------------------------------
// Kernel 1: QKV projection as bf16 MFMA GEMM (unchanged from R6).
//   qt,kt: [bh][n][32] bf16 (q pre-scaled into exp2 domain)
//   vtT:   [bh][32][n] bf16
// ---------------------------------------------------------------------------
__global__ __launch_bounds__(256) void qkv_proj_kernel(
    const float* __restrict__ x, const float* __restrict__ w,
    unsigned short* __restrict__ qt, unsigned short* __restrict__ kt,
    unsigned short* __restrict__ vtT)
{
    __shared__ unsigned short As[128 * 40];
    __shared__ unsigned short Bs[128 * 40];
    const int n0 = blockIdx.x * 128;
    const int o0 = blockIdx.y * 128;
    const int b  = blockIdx.z;
    const int tid  = (int)threadIdx.x;
    const int wave = tid >> 6;
    const int lane = tid & 63;
    const int li   = lane & 15;
    const int g    = lane >> 4;
    const int wm = (wave & 1) * 64;
    const int wn = (wave >> 1) * 64;
    const float* xb = x + (size_t)b * CDIM * NN;

    const int aco = (tid & 7) * 4;
    const int aor = tid >> 3;
    const int bn  = tid & 63;
    const int bcg = (tid >> 6) * 8;

    f32x4 acc[4][4];
#pragma unroll
    for (int i = 0; i < 4; ++i)
#pragma unroll
        for (int j = 0; j < 4; ++j) acc[i][j] = (f32x4){0.f, 0.f, 0.f, 0.f};

    for (int k0 = 0; k0 < CDIM; k0 += 32) {
        __syncthreads();
#pragma unroll
        for (int r = 0; r < 4; ++r) {
            const int o = aor + 32 * r;
            const float4 wv = *(const float4*)&w[(size_t)(o0 + o) * CDIM + k0 + aco];
            uint2 pk;
            pk.x = (unsigned)f2bf(wv.x) | ((unsigned)f2bf(wv.y) << 16);
            pk.y = (unsigned)f2bf(wv.z) | ((unsigned)f2bf(wv.w) << 16);
            *(uint2*)&As[o * 40 + aco] = pk;
        }
#pragma unroll
        for (int half = 0; half < 2; ++half) {
            const int n = bn + 64 * half;
            unsigned short tb[8];
#pragma unroll
            for (int j = 0; j < 8; ++j)
                tb[j] = f2bf(xb[(size_t)(k0 + bcg + j) * NN + n0 + n]);
            uint4 pk;
            pk.x = (unsigned)tb[0] | ((unsigned)tb[1] << 16);
            pk.y = (unsigned)tb[2] | ((unsigned)tb[3] << 16);
            pk.z = (unsigned)tb[4] | ((unsigned)tb[5] << 16);
            pk.w = (unsigned)tb[6] | ((unsigned)tb[7] << 16);
            *(uint4*)&Bs[n * 40 + bcg] = pk;
        }
        __syncthreads();

        bf16x8 af[4], bfr[4];
#pragma unroll
        for (int mt = 0; mt < 4; ++mt)
            af[mt] = *(const bf16x8*)&As[(wm + mt * 16 + li) * 40 + g * 8];
#pragma unroll
        for (int nt = 0; nt < 4; ++nt)
            bfr[nt] = *(const bf16x8*)&Bs[(wn + nt * 16 + li) * 40 + g * 8];
#pragma unroll
        for (int mt = 0; mt < 4; ++mt)
#pragma unroll
            for (int nt = 0; nt < 4; ++nt)
                acc[mt][nt] = __builtin_amdgcn_mfma_f32_16x16x32_bf16(
                    af[mt], bfr[nt], acc[mt][nt], 0, 0, 0);
    }

    const int sel = blockIdx.y;
    if (sel < 2) {
        unsigned short* dst = (sel == 0) ? qt : kt;
        const float mul = (sel == 0) ? SCALE_LOG2E : 1.0f;
#pragma unroll
        for (int mt = 0; mt < 4; ++mt) {
            const int ob = o0 + wm + mt * 16 + g * 4;
            const int d0 = ob & 31;
            const int h  = (ob & 127) >> 5;
            const size_t bh = (size_t)(b * NH + h);
#pragma unroll
            for (int nt = 0; nt < 4; ++nt) {
                const int n = n0 + wn + nt * 16 + li;
                const f32x4 a = acc[mt][nt];
                uint2 pk;
                pk.x = (unsigned)f2bf(a[0] * mul) | ((unsigned)f2bf(a[1] * mul) << 16);
                pk.y = (unsigned)f2bf(a[2] * mul) | ((unsigned)f2bf(a[3] * mul) << 16);
                *(uint2*)&dst[(bh * NN + n) * DH + d0] = pk;
            }
        }
    } else {
#pragma unroll
        for (int mt = 0; mt < 4; ++mt) {
            const int ob = o0 + wm + mt * 16 + g * 4;
            const int d0 = ob & 31;
            const int h  = (ob & 127) >> 5;
            const size_t bh = (size_t)(b * NH + h);
#pragma unroll
            for (int nt = 0; nt < 4; ++nt) {
                const int n = n0 + wn + nt * 16 + li;
                const f32x4 a = acc[mt][nt];
#pragma unroll
                for (int r = 0; r < 4; ++r)
                    vtT[(bh * DH + d0 + r) * (size_t)NN + n] = f2bf(a[r]);
            }
        }
    }
}

// ---------------------------------------------------------------------------
// Kernel 2: MFMA flash attention, NO LDS, NO transpose.
//   S^T = K·Q^T via 16x16x32  (C: i=lane&15, j=quad*4+reg)
//   P (exp'd, packed bf16x4) feeds PV DIRECTLY as A of 16x16x16
//   O += P·V via 16x16x16     (B = V^T[d=lane&15][j=quad*4+r], b64 load)
//   l via P·ones               (same A; rows i=quad*4+reg hold l_i)
// Partial O written to Op[part][bh][n][d] bf16; l to Lp.
// ---------------------------------------------------------------------------
__global__ __launch_bounds__(256) void attn_kernel(
    const unsigned short* __restrict__ qt, const unsigned short* __restrict__ kt,
    const unsigned short* __restrict__ vtT, unsigned short* __restrict__ Op,
    float* __restrict__ Lp)
{
    const int bh   = blockIdx.y;
    const int part = blockIdx.z;
    const int jbeg = part * JCHUNK;
    const int tid  = (int)threadIdx.x;
    const int wave = tid >> 6;
    const int lane = tid & 63;
    const int li   = lane & 15;
    const int g    = lane >> 4;
    const int i0   = blockIdx.x * 64 + wave * 16;

    const unsigned short* qb = qt  + (size_t)bh * NN * DH;
    const unsigned short* kb = kt  + (size_t)bh * NN * DH;
    const unsigned short* vb = vtT + (size_t)bh * DH * NN;

    bf16x8 qf = *(const bf16x8*)(qb + (size_t)(i0 + li) * DH + g * 8);

    bf16x4 ones4;
#pragma unroll
    for (int r = 0; r < 4; ++r) ones4[r] = (short)0x3F80;

    f32x4 Oa = {0.f, 0.f, 0.f, 0.f};   // O[i=4g+r][d=li]
    f32x4 Ob = {0.f, 0.f, 0.f, 0.f};   // O[i=4g+r][d=16+li]
    f32x4 Ls = {0.f, 0.f, 0.f, 0.f};   // l_{4g+r}

    const unsigned short* kp0 = kb + (size_t)(jbeg + li) * DH + g * 8;
    const unsigned short* kp1 = kp0 + 16 * DH;
    const unsigned short* vr0 = vb + (size_t)li * NN + jbeg + 4 * g;   // d=li
    const unsigned short* vr1 = vr0 + 16 * NN;                          // d=16+li

    bf16x8 kf0 = *(const bf16x8*)kp0;
    bf16x8 kf1 = *(const bf16x8*)kp1;
    bf16x4 va0 = *(const bf16x4*)(vr0);        // j-tile0, d-half0
    bf16x4 va1 = *(const bf16x4*)(vr0 + 16);   // j-tile1, d-half0
    bf16x4 vb0 = *(const bf16x4*)(vr1);        // j-tile0, d-half1
    bf16x4 vb1 = *(const bf16x4*)(vr1 + 16);   // j-tile1, d-half1

    for (int it = 0; it < NITER; ++it) {
        kp0 += 32 * DH; kp1 += 32 * DH; vr0 += 32; vr1 += 32;

        f32x4 z = {0.f, 0.f, 0.f, 0.f};
        f32x4 s0 = __builtin_amdgcn_mfma_f32_16x16x32_bf16(kf0, qf, z, 0, 0, 0);
        f32x4 s1 = __builtin_amdgcn_mfma_f32_16x16x32_bf16(kf1, qf, z, 0, 0, 0);

        // prefetch next-iter fragments (last-iter over-read stays inside ws)
        bf16x8 nk0 = *(const bf16x8*)kp0;
        bf16x8 nk1 = *(const bf16x8*)kp1;
        bf16x4 nva0 = *(const bf16x4*)(vr0);
        bf16x4 nva1 = *(const bf16x4*)(vr0 + 16);
        bf16x4 nvb0 = *(const bf16x4*)(vr1);
        bf16x4 nvb1 = *(const bf16x4*)(vr1 + 16);

        float p0[4], p1[4];
#pragma unroll
        for (int r = 0; r < 4; ++r) p0[r] = __builtin_amdgcn_exp2f(s0[r]);
#pragma unroll
        for (int r = 0; r < 4; ++r) p1[r] = __builtin_amdgcn_exp2f(s1[r]);

        bf16x4 pa = mk4(pack_trunc(p0[0], p0[1]), pack_trunc(p0[2], p0[3]));
        bf16x4 pb = mk4(pack_trunc(p1[0], p1[1]), pack_trunc(p1[2], p1[3]));

        Oa = mfma1616(pa, va0, Oa);
        Oa = mfma1616(pb, va1, Oa);
        Ob = mfma1616(pa, vb0, Ob);
        Ob = mfma1616(pb, vb1, Ob);
        Ls = mfma1616(pa, ones4, Ls);
        Ls = mfma1616(pb, ones4, Ls);

        kf0 = nk0; kf1 = nk1;
        va0 = nva0; va1 = nva1; vb0 = nvb0; vb1 = nvb1;
    }

    // epilogue: Op[part][bh][n = i0+4g+r][d]
#pragma unroll
    for (int r = 0; r < 4; ++r) {
        unsigned short* ob = Op + (size_t)part * SEG
                           + ((size_t)bh * NN + i0 + 4 * g + r) * DH;
        ob[li]      = f2bf(Oa[r]);
        ob[16 + li] = f2bf(Ob[r]);
    }
    if (li == 0) {
#pragma unroll
        for (int r = 0; r < 4; ++r)
            Lp[(size_t)part * LSEG + (size_t)bh * NN + i0 + 4 * g + r] = Ls[r];
    }
}

// ---------------------------------------------------------------------------
// Kernel 3: output projection as bf16 MFMA GEMM; B-staging folds the 4-way
// partial-O reduction (now ONE b128 load per part) and the 1/l normalization.
// ---------------------------------------------------------------------------
__global__ __launch_bounds__(256) void out_proj_kernel(
    const unsigned short* __restrict__ Op, const float* __restrict__ Lp,
    const float* __restrict__ w, const float* __restrict__ bias,
    float* __restrict__ y)
{
    __shared__ unsigned short As[128 * 40];
    __shared__ unsigned short Bs[128 * 40];
    __shared__ float Linv[4][128];
    const int n0 = blockIdx.x * 128;
    const int o0 = blockIdx.y * 128;
    const int b  = blockIdx.z;
    const int tid  = (int)threadIdx.x;
    const int wave = tid >> 6;
    const int lane = tid & 63;
    const int li   = lane & 15;
    const int g    = lane >> 4;
    const int wm = (wave & 1) * 64;
    const int wn = (wave >> 1) * 64;

    const int aco = (tid & 7) * 4;
    const int aor = tid >> 3;
    const int bn  = tid & 63;
    const int bcg = (tid >> 6) * 8;

    {
        const int h = tid >> 6, nb = tid & 63;
#pragma unroll
        for (int half = 0; half < 2; ++half) {
            const int n = nb + 64 * half;
            float s = 0.f;
#pragma unroll
            for (int p = 0; p < PPARTS; ++p)
                s += Lp[(size_t)p * LSEG + (size_t)(b * NH + h) * NN + n0 + n];
            Linv[h][n] = 1.0f / s;
        }
    }

    f32x4 acc[4][4];
#pragma unroll
    for (int i = 0; i < 4; ++i)
#pragma unroll
        for (int j = 0; j < 4; ++j) acc[i][j] = (f32x4){0.f, 0.f, 0.f, 0.f};

    for (int k0 = 0; k0 < HIDC; k0 += 32) {
        __syncthreads();
#pragma unroll
        for (int r = 0; r < 4; ++r) {
            const int o = aor + 32 * r;
            const float4 wv = *(const float4*)&w[(size_t)(o0 + o) * HIDC + k0 + aco];
            uint2 pk;
            pk.x = (unsigned)f2bf(wv.x) | ((unsigned)f2bf(wv.y) << 16);
            pk.y = (unsigned)f2bf(wv.z) | ((unsigned)f2bf(wv.w) << 16);
            *(uint2*)&As[o * 40 + aco] = pk;
        }
        const int h = k0 >> 5;                      // BK=32 == one head
        const size_t bh = (size_t)(b * NH + h);
#pragma unroll
        for (int half = 0; half < 2; ++half) {
            const int n = bn + 64 * half;
            const float linv = Linv[h][n];
            const size_t obase = ((size_t)bh * NN + n0 + n) * DH + bcg;
            float s[8] = {0.f, 0.f, 0.f, 0.f, 0.f, 0.f, 0.f, 0.f};
#pragma unroll
            for (int p = 0; p < PPARTS; ++p) {
                const uint4 u = *(const uint4*)&Op[(size_t)p * SEG + obase];
                s[0] += bflo(u.x); s[1] += bfhi(u.x);
                s[2] += bflo(u.y); s[3] += bfhi(u.y);
                s[4] += bflo(u.z); s[5] += bfhi(u.z);
                s[6] += bflo(u.w); s[7] += bfhi(u.w);
            }
            uint4 pk;
            pk.x = (unsigned)f2bf(s[0] * linv) | ((unsigned)f2bf(s[1] * linv) << 16);
            pk.y = (unsigned)f2bf(s[2] * linv) | ((unsigned)f2bf(s[3] * linv) << 16);
            pk.z = (unsigned)f2bf(s[4] * linv) | ((unsigned)f2bf(s[5] * linv) << 16);
            pk.w = (unsigned)f2bf(s[6] * linv) | ((unsigned)f2bf(s[7] * linv) << 16);
            *(uint4*)&Bs[n * 40 + bcg] = pk;
        }
        __syncthreads();

        bf16x8 af[4], bfr[4];
#pragma unroll
        for (int mt = 0; mt < 4; ++mt)
            af[mt] = *(const bf16x8*)&As[(wm + mt * 16 + li) * 40 + g * 8];
#pragma unroll
        for (int nt = 0; nt < 4; ++nt)
            bfr[nt] = *(const bf16x8*)&Bs[(wn + nt * 16 + li) * 40 + g * 8];
#pragma unroll
        for (int mt = 0; mt < 4; ++mt)
#pragma unroll
            for (int nt = 0; nt < 4; ++nt)
                acc[mt][nt] = __builtin_amdgcn_mfma_f32_16x16x32_bf16(
                    af[mt], bfr[nt], acc[mt][nt], 0, 0, 0);
    }

#pragma unroll
    for (int mt = 0; mt < 4; ++mt) {
        const int ob = o0 + wm + mt * 16 + g * 4;
        const float b0 = bias[ob], b1 = bias[ob + 1], b2 = bias[ob + 2], b3 = bias[ob + 3];
#pragma unroll
        for (int nt = 0; nt < 4; ++nt) {
            const int n = n0 + wn + nt * 16 + li;
            const f32x4 a = acc[mt][nt];
            float* yb = y + ((size_t)(b * CDIM + ob)) * NN + n;
            yb[0]              = a[0] + b0;
            yb[(size_t)NN]     = a[1] + b1;
            yb[(size_t)2 * NN] = a[2] + b2;
            yb[(size_t)3 * NN] = a[3] + b3;
        }
    }
}

// ---------------------------------------------------------------------------
extern "C" void kernel_launch(void* const* d_in, const int* in_sizes, int n_in,
                              void* d_out, int out_size, void* d_ws, size_t ws_size,
                              hipStream_t stream)
{
    (void)in_sizes; (void)n_in; (void)out_size; (void)ws_size;
    const float* x     = (const float*)d_in[0];
    const float* w_qkv = (const float*)d_in[1];
    const float* w_out = (const float*)d_in[2];
    const float* b_out = (const float*)d_in[3];
    float* y = (float*)d_out;

    unsigned short* qt  = (unsigned short*)d_ws;
    unsigned short* kt  = qt + SEG;
    unsigned short* vtT = kt + SEG;
    unsigned short* Op  = vtT + SEG;                     // PPARTS x SEG bf16
    float* Lp = (float*)(Op + (size_t)PPARTS * SEG);     // PPARTS x LSEG fp32

    dim3 g1(NN / 128, OC3 / 128, NB);                    // 18 x 3 x 8
    qkv_proj_kernel<<<g1, 256, 0, stream>>>(x, w_qkv, qt, kt, vtT);

    dim3 g2(NN / 64, NB * NH, PPARTS);                   // 36 x 32 x 4
    attn_kernel<<<g2, 256, 0, stream>>>(qt, kt, vtT, Op, Lp);

    dim3 g3(NN / 128, CDIM / 128, NB);                   // 18 x 2 x 8
    out_proj_kernel<<<g3, 256, 0, stream>>>(Op, Lp, w_out, b_out, y);
}

// Round 8
// 169.759 us; speedup vs baseline: 1.6475x; 1.6475x over previous
//
#include <hip/hip_runtime.h>
#include <math.h>

#define NB    8
#define CDIM  256
#define NN    2304
#define NH    4
#define DH    32
#define HIDC  128
#define OC3   384
#define SCALE_LOG2E 0.25503524964550864f         // 32^-0.5 * log2(e)
#define SEG   2359296                            // NB*NH*NN*DH
#define LSEG  73728                              // NB*NH*NN
#define PPARTS 4
#define JCHUNK 576                               // NN / PPARTS
#define NITER  18                                // JCHUNK / 32

typedef short  bf16x8 __attribute__((ext_vector_type(8)));
typedef float  f32x4  __attribute__((ext_vector_type(4)));

__device__ __forceinline__ unsigned short f2bf(float f) {
    union { float f; unsigned u; } a; a.f = f;
    unsigned r = a.u + 0x7fffu + ((a.u >> 16) & 1u);   // RNE
    return (unsigned short)(r >> 16);
}

__device__ __forceinline__ unsigned pack_trunc(float lo, float hi) {
    union { float f; unsigned u; } a, b; a.f = lo; b.f = hi;
    return (b.u & 0xFFFF0000u) | (a.u >> 16);          // bf16x2, truncated
}

__device__ __forceinline__ float bf2f(unsigned short u) {
    union { unsigned u; float f; } c; c.u = ((unsigned)u) << 16; return c.f;
}

// ---------------------------------------------------------------------------
// Kernel 1: QKV projection as bf16 MFMA GEMM (R6, proven).
//   qt,kt: [bh][n][32] bf16 (q pre-scaled into exp2 domain)
//   vtT:   [bh][32][n] bf16
// ---------------------------------------------------------------------------
__global__ __launch_bounds__(256) void qkv_proj_kernel(
    const float* __restrict__ x, const float* __restrict__ w,
    unsigned short* __restrict__ qt, unsigned short* __restrict__ kt,
    unsigned short* __restrict__ vtT)
{
    __shared__ unsigned short As[128 * 40];
    __shared__ unsigned short Bs[128 * 40];
    const int n0 = blockIdx.x * 128;
    const int o0 = blockIdx.y * 128;
    const int b  = blockIdx.z;
    const int tid  = (int)threadIdx.x;
    const int wave = tid >> 6;
    const int lane = tid & 63;
    const int li   = lane & 15;
    const int g    = lane >> 4;
    const int wm = (wave & 1) * 64;
    const int wn = (wave >> 1) * 64;
    const float* xb = x + (size_t)b * CDIM * NN;

    const int aco = (tid & 7) * 4;
    const int aor = tid >> 3;
    const int bn  = tid & 63;
    const int bcg = (tid >> 6) * 8;

    f32x4 acc[4][4];
#pragma unroll
    for (int i = 0; i < 4; ++i)
#pragma unroll
        for (int j = 0; j < 4; ++j) acc[i][j] = (f32x4){0.f, 0.f, 0.f, 0.f};

    for (int k0 = 0; k0 < CDIM; k0 += 32) {
        __syncthreads();
#pragma unroll
        for (int r = 0; r < 4; ++r) {
            const int o = aor + 32 * r;
            const float4 wv = *(const float4*)&w[(size_t)(o0 + o) * CDIM + k0 + aco];
            uint2 pk;
            pk.x = (unsigned)f2bf(wv.x) | ((unsigned)f2bf(wv.y) << 16);
            pk.y = (unsigned)f2bf(wv.z) | ((unsigned)f2bf(wv.w) << 16);
            *(uint2*)&As[o * 40 + aco] = pk;
        }
#pragma unroll
        for (int half = 0; half < 2; ++half) {
            const int n = bn + 64 * half;
            unsigned short tb[8];
#pragma unroll
            for (int j = 0; j < 8; ++j)
                tb[j] = f2bf(xb[(size_t)(k0 + bcg + j) * NN + n0 + n]);
            uint4 pk;
            pk.x = (unsigned)tb[0] | ((unsigned)tb[1] << 16);
            pk.y = (unsigned)tb[2] | ((unsigned)tb[3] << 16);
            pk.z = (unsigned)tb[4] | ((unsigned)tb[5] << 16);
            pk.w = (unsigned)tb[6] | ((unsigned)tb[7] << 16);
            *(uint4*)&Bs[n * 40 + bcg] = pk;
        }
        __syncthreads();

        bf16x8 af[4], bfr[4];
#pragma unroll
        for (int mt = 0; mt < 4; ++mt)
            af[mt] = *(const bf16x8*)&As[(wm + mt * 16 + li) * 40 + g * 8];
#pragma unroll
        for (int nt = 0; nt < 4; ++nt)
            bfr[nt] = *(const bf16x8*)&Bs[(wn + nt * 16 + li) * 40 + g * 8];
#pragma unroll
        for (int mt = 0; mt < 4; ++mt)
#pragma unroll
            for (int nt = 0; nt < 4; ++nt)
                acc[mt][nt] = __builtin_amdgcn_mfma_f32_16x16x32_bf16(
                    af[mt], bfr[nt], acc[mt][nt], 0, 0, 0);
    }

    const int sel = blockIdx.y;
    if (sel < 2) {
        unsigned short* dst = (sel == 0) ? qt : kt;
        const float mul = (sel == 0) ? SCALE_LOG2E : 1.0f;
#pragma unroll
        for (int mt = 0; mt < 4; ++mt) {
            const int ob = o0 + wm + mt * 16 + g * 4;
            const int d0 = ob & 31;
            const int h  = (ob & 127) >> 5;
            const size_t bh = (size_t)(b * NH + h);
#pragma unroll
            for (int nt = 0; nt < 4; ++nt) {
                const int n = n0 + wn + nt * 16 + li;
                const f32x4 a = acc[mt][nt];
                uint2 pk;
                pk.x = (unsigned)f2bf(a[0] * mul) | ((unsigned)f2bf(a[1] * mul) << 16);
                pk.y = (unsigned)f2bf(a[2] * mul) | ((unsigned)f2bf(a[3] * mul) << 16);
                *(uint2*)&dst[(bh * NN + n) * DH + d0] = pk;
            }
        }
    } else {
#pragma unroll
        for (int mt = 0; mt < 4; ++mt) {
            const int ob = o0 + wm + mt * 16 + g * 4;
            const int d0 = ob & 31;
            const int h  = (ob & 127) >> 5;
            const size_t bh = (size_t)(b * NH + h);
#pragma unroll
            for (int nt = 0; nt < 4; ++nt) {
                const int n = n0 + wn + nt * 16 + li;
                const f32x4 a = acc[mt][nt];
#pragma unroll
                for (int r = 0; r < 4; ++r)
                    vtT[(bh * DH + d0 + r) * (size_t)NN + n] = f2bf(a[r]);
            }
        }
    }
}

// ---------------------------------------------------------------------------
// Kernel 2: MFMA flash attention, unstable softmax, j-split.
// v8: 32 queries per wave (two independent S/PV chains sharing the K/V
// loads -> 2x ILP, half the waves/load-stall events), R6-proven LDS
// transpose per chain, XCD-aware 1D grid swizzle so all i-blocks of one
// (bh,part) K/V chunk land on one XCD (16 x 147KB = 2.4MB < 4MB L2).
// ---------------------------------------------------------------------------
__global__ __launch_bounds__(256) void attn_kernel(
    const unsigned short* __restrict__ qt, const unsigned short* __restrict__ kt,
    const unsigned short* __restrict__ vtT, unsigned short* __restrict__ Op,
    float* __restrict__ Lp)
{
    __shared__ unsigned short Pl[4][2][16 * 40];
    const int Lb  = (int)blockIdx.x;          // 0..2303
    const int xcd = Lb & 7;
    const int t   = Lb >> 3;                  // 0..287
    const int ib  = t % 18;                   // i-block
    const int grp = (t / 18) * 8 + xcd;       // 0..127, XCD-resident group
    const int bh  = grp >> 2;
    const int part = grp & 3;
    const int jbeg = part * JCHUNK;

    const int tid  = (int)threadIdx.x;
    const int wave = tid >> 6;
    const int lane = tid & 63;
    const int li   = lane & 15;
    const int g    = lane >> 4;
    const int i0   = ib * 128 + wave * 32;

    const unsigned short* qb = qt  + (size_t)bh * NN * DH;
    const unsigned short* kb = kt  + (size_t)bh * NN * DH;
    const unsigned short* vb = vtT + (size_t)bh * DH * NN;

    bf16x8 qfA = *(const bf16x8*)(qb + (size_t)(i0 + li) * DH + g * 8);
    bf16x8 qfB = *(const bf16x8*)(qb + (size_t)(i0 + 16 + li) * DH + g * 8);

    bf16x8 ones;
#pragma unroll
    for (int r = 0; r < 8; ++r) ones[r] = (short)0x3F80;

    f32x4 O0A = {0.f,0.f,0.f,0.f}, O1A = {0.f,0.f,0.f,0.f}, LsA = {0.f,0.f,0.f,0.f};
    f32x4 O0B = {0.f,0.f,0.f,0.f}, O1B = {0.f,0.f,0.f,0.f}, LsB = {0.f,0.f,0.f,0.f};
    unsigned short* plA = &Pl[wave][0][0];
    unsigned short* plB = &Pl[wave][1][0];
    const int pw = li * 40;

    const unsigned short* kp0 = kb + (size_t)(jbeg + li) * DH + g * 8;
    const unsigned short* kp1 = kp0 + 16 * DH;
    const unsigned short* vp0 = vb + (size_t)li * NN + jbeg + g * 8;
    const unsigned short* vp1 = vp0 + 16 * NN;

    bf16x8 kf0 = *(const bf16x8*)kp0;
    bf16x8 kf1 = *(const bf16x8*)kp1;
    bf16x8 vf0 = *(const bf16x8*)vp0;
    bf16x8 vf1 = *(const bf16x8*)vp1;

    for (int it = 0; it < NITER; ++it) {
        kp0 += 32 * DH; kp1 += 32 * DH; vp0 += 32; vp1 += 32;

        f32x4 z = {0.f, 0.f, 0.f, 0.f};
        f32x4 s0A = __builtin_amdgcn_mfma_f32_16x16x32_bf16(kf0, qfA, z, 0, 0, 0);
        f32x4 s0B = __builtin_amdgcn_mfma_f32_16x16x32_bf16(kf0, qfB, z, 0, 0, 0);
        f32x4 s1A = __builtin_amdgcn_mfma_f32_16x16x32_bf16(kf1, qfA, z, 0, 0, 0);
        f32x4 s1B = __builtin_amdgcn_mfma_f32_16x16x32_bf16(kf1, qfB, z, 0, 0, 0);

        // prefetch next-iter fragments (last-iter over-read stays inside ws)
        bf16x8 nk0 = *(const bf16x8*)kp0;
        bf16x8 nk1 = *(const bf16x8*)kp1;
        bf16x8 nv0 = *(const bf16x8*)vp0;
        bf16x8 nv1 = *(const bf16x8*)vp1;

        float p0A[4], p1A[4], p0B[4], p1B[4];
#pragma unroll
        for (int r = 0; r < 4; ++r) {
            p0A[r] = __builtin_amdgcn_exp2f(s0A[r]);
            p1A[r] = __builtin_amdgcn_exp2f(s1A[r]);
            p0B[r] = __builtin_amdgcn_exp2f(s0B[r]);
            p1B[r] = __builtin_amdgcn_exp2f(s1B[r]);
        }

        uint2 wa, wb;
        wa.x = pack_trunc(p0A[0], p0A[1]);  wa.y = pack_trunc(p0A[2], p0A[3]);
        wb.x = pack_trunc(p1A[0], p1A[1]);  wb.y = pack_trunc(p1A[2], p1A[3]);
        *(uint2*)&plA[pw + 4 * g]      = wa;
        *(uint2*)&plA[pw + 16 + 4 * g] = wb;
        wa.x = pack_trunc(p0B[0], p0B[1]);  wa.y = pack_trunc(p0B[2], p0B[3]);
        wb.x = pack_trunc(p1B[0], p1B[1]);  wb.y = pack_trunc(p1B[2], p1B[3]);
        *(uint2*)&plB[pw + 4 * g]      = wa;
        *(uint2*)&plB[pw + 16 + 4 * g] = wb;

        bf16x8 pfA = *(const bf16x8*)&plA[pw + g * 8];
        bf16x8 pfB = *(const bf16x8*)&plB[pw + g * 8];

        O0A = __builtin_amdgcn_mfma_f32_16x16x32_bf16(vf0,  pfA, O0A, 0, 0, 0);
        O0B = __builtin_amdgcn_mfma_f32_16x16x32_bf16(vf0,  pfB, O0B, 0, 0, 0);
        O1A = __builtin_amdgcn_mfma_f32_16x16x32_bf16(vf1,  pfA, O1A, 0, 0, 0);
        O1B = __builtin_amdgcn_mfma_f32_16x16x32_bf16(vf1,  pfB, O1B, 0, 0, 0);
        LsA = __builtin_amdgcn_mfma_f32_16x16x32_bf16(ones, pfA, LsA, 0, 0, 0);
        LsB = __builtin_amdgcn_mfma_f32_16x16x32_bf16(ones, pfB, LsB, 0, 0, 0);

        kf0 = nk0; kf1 = nk1; vf0 = nv0; vf1 = nv1;
    }

    // epilogue: Op[part][bh][d][n] bf16 (O^T C-layout: col i=li, row d)
    unsigned short* obA = Op + (size_t)part * SEG + (size_t)bh * DH * NN + i0 + li;
    unsigned short* obB = obA + 16;
#pragma unroll
    for (int r = 0; r < 4; ++r) {
        obA[(size_t)(4 * g + r)      * NN] = f2bf(O0A[r]);
        obA[(size_t)(16 + 4 * g + r) * NN] = f2bf(O1A[r]);
        obB[(size_t)(4 * g + r)      * NN] = f2bf(O0B[r]);
        obB[(size_t)(16 + 4 * g + r) * NN] = f2bf(O1B[r]);
    }
    if (g == 0) {
        Lp[(size_t)part * LSEG + (size_t)bh * NN + i0 + li]      = LsA[0];
        Lp[(size_t)part * LSEG + (size_t)bh * NN + i0 + 16 + li] = LsB[0];
    }
}

// ---------------------------------------------------------------------------
// Kernel 3: output projection as bf16 MFMA GEMM (R6, proven); B-staging folds
// the 4-way bf16 partial-O reduction and the 1/l normalization.
// ---------------------------------------------------------------------------
__global__ __launch_bounds__(256) void out_proj_kernel(
    const unsigned short* __restrict__ Op, const float* __restrict__ Lp,
    const float* __restrict__ w, const float* __restrict__ bias,
    float* __restrict__ y)
{
    __shared__ unsigned short As[128 * 40];
    __shared__ unsigned short Bs[128 * 40];
    __shared__ float Linv[4][128];
    const int n0 = blockIdx.x * 128;
    const int o0 = blockIdx.y * 128;
    const int b  = blockIdx.z;
    const int tid  = (int)threadIdx.x;
    const int wave = tid >> 6;
    const int lane = tid & 63;
    const int li   = lane & 15;
    const int g    = lane >> 4;
    const int wm = (wave & 1) * 64;
    const int wn = (wave >> 1) * 64;

    const int aco = (tid & 7) * 4;
    const int aor = tid >> 3;
    const int bn  = tid & 63;
    const int bcg = (tid >> 6) * 8;

    {
        const int h = tid >> 6, nb = tid & 63;
#pragma unroll
        for (int half = 0; half < 2; ++half) {
            const int n = nb + 64 * half;
            float s = 0.f;
#pragma unroll
            for (int p = 0; p < PPARTS; ++p)
                s += Lp[(size_t)p * LSEG + (size_t)(b * NH + h) * NN + n0 + n];
            Linv[h][n] = 1.0f / s;
        }
    }

    f32x4 acc[4][4];
#pragma unroll
    for (int i = 0; i < 4; ++i)
#pragma unroll
        for (int j = 0; j < 4; ++j) acc[i][j] = (f32x4){0.f, 0.f, 0.f, 0.f};

    for (int k0 = 0; k0 < HIDC; k0 += 32) {
        __syncthreads();
#pragma unroll
        for (int r = 0; r < 4; ++r) {
            const int o = aor + 32 * r;
            const float4 wv = *(const float4*)&w[(size_t)(o0 + o) * HIDC + k0 + aco];
            uint2 pk;
            pk.x = (unsigned)f2bf(wv.x) | ((unsigned)f2bf(wv.y) << 16);
            pk.y = (unsigned)f2bf(wv.z) | ((unsigned)f2bf(wv.w) << 16);
            *(uint2*)&As[o * 40 + aco] = pk;
        }
        const int h = k0 >> 5;                      // BK=32 == one head
        const size_t bh = (size_t)(b * NH + h);
#pragma unroll
        for (int half = 0; half < 2; ++half) {
            const int n = bn + 64 * half;
            const float linv = Linv[h][n];
            unsigned short tb[8];
#pragma unroll
            for (int j = 0; j < 8; ++j) {
                const int d = bcg + j;
                const size_t base = (bh * DH + d) * (size_t)NN + n0 + n;
                float s = 0.f;
#pragma unroll
                for (int p = 0; p < PPARTS; ++p) s += bf2f(Op[(size_t)p * SEG + base]);
                tb[j] = f2bf(s * linv);
            }
            uint4 pk;
            pk.x = (unsigned)tb[0] | ((unsigned)tb[1] << 16);
            pk.y = (unsigned)tb[2] | ((unsigned)tb[3] << 16);
            pk.z = (unsigned)tb[4] | ((unsigned)tb[5] << 16);
            pk.w = (unsigned)tb[6] | ((unsigned)tb[7] << 16);
            *(uint4*)&Bs[n * 40 + bcg] = pk;
        }
        __syncthreads();

        bf16x8 af[4], bfr[4];
#pragma unroll
        for (int mt = 0; mt < 4; ++mt)
            af[mt] = *(const bf16x8*)&As[(wm + mt * 16 + li) * 40 + g * 8];
#pragma unroll
        for (int nt = 0; nt < 4; ++nt)
            bfr[nt] = *(const bf16x8*)&Bs[(wn + nt * 16 + li) * 40 + g * 8];
#pragma unroll
        for (int mt = 0; mt < 4; ++mt)
#pragma unroll
            for (int nt = 0; nt < 4; ++nt)
                acc[mt][nt] = __builtin_amdgcn_mfma_f32_16x16x32_bf16(
                    af[mt], bfr[nt], acc[mt][nt], 0, 0, 0);
    }

#pragma unroll
    for (int mt = 0; mt < 4; ++mt) {
        const int ob = o0 + wm + mt * 16 + g * 4;
        const float b0 = bias[ob], b1 = bias[ob + 1], b2 = bias[ob + 2], b3 = bias[ob + 3];
#pragma unroll
        for (int nt = 0; nt < 4; ++nt) {
            const int n = n0 + wn + nt * 16 + li;
            const f32x4 a = acc[mt][nt];
            float* yb = y + ((size_t)(b * CDIM + ob)) * NN + n;
            yb[0]              = a[0] + b0;
            yb[(size_t)NN]     = a[1] + b1;
            yb[(size_t)2 * NN] = a[2] + b2;
            yb[(size_t)3 * NN] = a[3] + b3;
        }
    }
}

// ---------------------------------------------------------------------------
extern "C" void kernel_launch(void* const* d_in, const int* in_sizes, int n_in,
                              void* d_out, int out_size, void* d_ws, size_t ws_size,
                              hipStream_t stream)
{
    (void)in_sizes; (void)n_in; (void)out_size; (void)ws_size;
    const float* x     = (const float*)d_in[0];
    const float* w_qkv = (const float*)d_in[1];
    const float* w_out = (const float*)d_in[2];
    const float* b_out = (const float*)d_in[3];
    float* y = (float*)d_out;

    unsigned short* qt  = (unsigned short*)d_ws;
    unsigned short* kt  = qt + SEG;
    unsigned short* vtT = kt + SEG;
    unsigned short* Op  = vtT + SEG;                     // PPARTS x SEG bf16
    float* Lp = (float*)(Op + (size_t)PPARTS * SEG);     // PPARTS x LSEG fp32

    dim3 g1(NN / 128, OC3 / 128, NB);                    // 18 x 3 x 8
    qkv_proj_kernel<<<g1, 256, 0, stream>>>(x, w_qkv, qt, kt, vtT);

    dim3 g2(2304);                                       // 18 i-blocks x 32 bh x 4 parts, XCD-swizzled
    attn_kernel<<<g2, 256, 0, stream>>>(qt, kt, vtT, Op, Lp);

    dim3 g3(NN / 128, CDIM / 128, NB);                   // 18 x 2 x 8
    out_proj_kernel<<<g3, 256, 0, stream>>>(Op, Lp, w_out, b_out, y);
}

// Round 9
// 169.374 us; speedup vs baseline: 1.6512x; 1.0023x over previous
//
#include <hip/hip_runtime.h>
#include <math.h>

#define NB    8
#define CDIM  256
#define NN    2304
#define NH    4
#define DH    32
#define HIDC  128
#define OC3   384
#define SCALE_LOG2E 0.25503524964550864f         // 32^-0.5 * log2(e)
#define SEG   2359296                            // NB*NH*NN*DH
#define LSEG  73728                              // NB*NH*NN
#define PPARTS 4
#define JCHUNK 576                               // NN / PPARTS
#define NITER  18                                // JCHUNK / 32

typedef short  bf16x8 __attribute__((ext_vector_type(8)));
typedef float  f32x4  __attribute__((ext_vector_type(4)));

__device__ __forceinline__ unsigned short f2bf(float f) {
    union { float f; unsigned u; } a; a.f = f;
    unsigned r = a.u + 0x7fffu + ((a.u >> 16) & 1u);   // RNE
    return (unsigned short)(r >> 16);
}

__device__ __forceinline__ unsigned pack_trunc(float lo, float hi) {
    union { float f; unsigned u; } a, b; a.f = lo; b.f = hi;
    return (b.u & 0xFFFF0000u) | (a.u >> 16);          // bf16x2, truncated
}

__device__ __forceinline__ float bflo(unsigned u) {
    union { unsigned u; float f; } c; c.u = u << 16; return c.f;
}
__device__ __forceinline__ float bfhi(unsigned u) {
    union { unsigned u; float f; } c; c.u = u & 0xFFFF0000u; return c.f;
}

// ---------------------------------------------------------------------------
// Kernel 1: QKV projection as bf16 MFMA GEMM.  X staging vectorized:
// 4x float4 loads + register transpose + 4x b64 LDS writes per thread/iter.
//   qt,kt: [bh][n][32] bf16 (q pre-scaled into exp2 domain)
//   vtT:   [bh][32][n] bf16
// ---------------------------------------------------------------------------
__global__ __launch_bounds__(256) void qkv_proj_kernel(
    const float* __restrict__ x, const float* __restrict__ w,
    unsigned short* __restrict__ qt, unsigned short* __restrict__ kt,
    unsigned short* __restrict__ vtT)
{
    __shared__ unsigned short As[128 * 40];
    __shared__ unsigned short Bs[128 * 40];
    const int n0 = blockIdx.x * 128;
    const int o0 = blockIdx.y * 128;
    const int b  = blockIdx.z;
    const int tid  = (int)threadIdx.x;
    const int wave = tid >> 6;
    const int lane = tid & 63;
    const int li   = lane & 15;
    const int g    = lane >> 4;
    const int wm = (wave & 1) * 64;
    const int wn = (wave >> 1) * 64;
    const float* xb = x + (size_t)b * CDIM * NN;

    const int aco = (tid & 7) * 4;    // A staging: c offset
    const int aor = tid >> 3;         // A staging: o row 0..31
    const int n4  = (tid & 31) * 4;   // B staging: n base
    const int c4  = (tid >> 5) * 4;   // B staging: c base

    f32x4 acc[4][4];
#pragma unroll
    for (int i = 0; i < 4; ++i)
#pragma unroll
        for (int j = 0; j < 4; ++j) acc[i][j] = (f32x4){0.f, 0.f, 0.f, 0.f};

    for (int k0 = 0; k0 < CDIM; k0 += 32) {
        __syncthreads();
#pragma unroll
        for (int r = 0; r < 4; ++r) {
            const int o = aor + 32 * r;
            const float4 wv = *(const float4*)&w[(size_t)(o0 + o) * CDIM + k0 + aco];
            uint2 pk;
            pk.x = (unsigned)f2bf(wv.x) | ((unsigned)f2bf(wv.y) << 16);
            pk.y = (unsigned)f2bf(wv.z) | ((unsigned)f2bf(wv.w) << 16);
            *(uint2*)&As[o * 40 + aco] = pk;
        }
        float4 xv[4];
#pragma unroll
        for (int dd = 0; dd < 4; ++dd)
            xv[dd] = *(const float4*)&xb[(size_t)(k0 + c4 + dd) * NN + n0 + n4];
#pragma unroll
        for (int j = 0; j < 4; ++j) {
            uint2 pk;
            pk.x = (unsigned)f2bf(((const float*)&xv[0])[j])
                 | ((unsigned)f2bf(((const float*)&xv[1])[j]) << 16);
            pk.y = (unsigned)f2bf(((const float*)&xv[2])[j])
                 | ((unsigned)f2bf(((const float*)&xv[3])[j]) << 16);
            *(uint2*)&Bs[(n4 + j) * 40 + c4] = pk;
        }
        __syncthreads();

        bf16x8 af[4], bfr[4];
#pragma unroll
        for (int mt = 0; mt < 4; ++mt)
            af[mt] = *(const bf16x8*)&As[(wm + mt * 16 + li) * 40 + g * 8];
#pragma unroll
        for (int nt = 0; nt < 4; ++nt)
            bfr[nt] = *(const bf16x8*)&Bs[(wn + nt * 16 + li) * 40 + g * 8];
#pragma unroll
        for (int mt = 0; mt < 4; ++mt)
#pragma unroll
            for (int nt = 0; nt < 4; ++nt)
                acc[mt][nt] = __builtin_amdgcn_mfma_f32_16x16x32_bf16(
                    af[mt], bfr[nt], acc[mt][nt], 0, 0, 0);
    }

    const int sel = blockIdx.y;
    if (sel < 2) {
        unsigned short* dst = (sel == 0) ? qt : kt;
        const float mul = (sel == 0) ? SCALE_LOG2E : 1.0f;
#pragma unroll
        for (int mt = 0; mt < 4; ++mt) {
            const int ob = o0 + wm + mt * 16 + g * 4;
            const int d0 = ob & 31;
            const int h  = (ob & 127) >> 5;
            const size_t bh = (size_t)(b * NH + h);
#pragma unroll
            for (int nt = 0; nt < 4; ++nt) {
                const int n = n0 + wn + nt * 16 + li;
                const f32x4 a = acc[mt][nt];
                uint2 pk;
                pk.x = (unsigned)f2bf(a[0] * mul) | ((unsigned)f2bf(a[1] * mul) << 16);
                pk.y = (unsigned)f2bf(a[2] * mul) | ((unsigned)f2bf(a[3] * mul) << 16);
                *(uint2*)&dst[(bh * NN + n) * DH + d0] = pk;
            }
        }
    } else {
#pragma unroll
        for (int mt = 0; mt < 4; ++mt) {
            const int ob = o0 + wm + mt * 16 + g * 4;
            const int d0 = ob & 31;
            const int h  = (ob & 127) >> 5;
            const size_t bh = (size_t)(b * NH + h);
#pragma unroll
            for (int nt = 0; nt < 4; ++nt) {
                const int n = n0 + wn + nt * 16 + li;
                const f32x4 a = acc[mt][nt];
#pragma unroll
                for (int r = 0; r < 4; ++r)
                    vtT[(bh * DH + d0 + r) * (size_t)NN + n] = f2bf(a[r]);
            }
        }
    }
}

// ---------------------------------------------------------------------------
// Kernel 2: MFMA flash attention (R8 structure) + XOR-swizzled LDS transpose.
// Pl row stride 32 shorts, chunk c (4 shorts) stored at c ^ (li&6):
//   - b64 writes: 4-way bank aliasing (the b64 floor), was 8-way
//   - b128 reads: start chunk (2g)^(li&6) is even -> contiguous, 16B-aligned
// 32 queries/wave (2 chains), XCD-swizzled 1D grid, j-split over parts.
// ---------------------------------------------------------------------------
__global__ __launch_bounds__(256) void attn_kernel(
    const unsigned short* __restrict__ qt, const unsigned short* __restrict__ kt,
    const unsigned short* __restrict__ vtT, unsigned short* __restrict__ Op,
    float* __restrict__ Lp)
{
    __shared__ unsigned short Pl[4][2][16 * 32];
    const int Lb  = (int)blockIdx.x;          // 0..2303
    const int xcd = Lb & 7;
    const int t   = Lb >> 3;                  // 0..287
    const int ib  = t % 18;                   // i-block
    const int grp = (t / 18) * 8 + xcd;       // 0..127, XCD-resident group
    const int bh  = grp >> 2;
    const int part = grp & 3;
    const int jbeg = part * JCHUNK;

    const int tid  = (int)threadIdx.x;
    const int wave = tid >> 6;
    const int lane = tid & 63;
    const int li   = lane & 15;
    const int g    = lane >> 4;
    const int i0   = ib * 128 + wave * 32;

    const unsigned short* qb = qt  + (size_t)bh * NN * DH;
    const unsigned short* kb = kt  + (size_t)bh * NN * DH;
    const unsigned short* vb = vtT + (size_t)bh * DH * NN;

    bf16x8 qfA = *(const bf16x8*)(qb + (size_t)(i0 + li) * DH + g * 8);
    bf16x8 qfB = *(const bf16x8*)(qb + (size_t)(i0 + 16 + li) * DH + g * 8);

    bf16x8 ones;
#pragma unroll
    for (int r = 0; r < 8; ++r) ones[r] = (short)0x3F80;

    f32x4 O0A = {0.f,0.f,0.f,0.f}, O1A = {0.f,0.f,0.f,0.f}, LsA = {0.f,0.f,0.f,0.f};
    f32x4 O0B = {0.f,0.f,0.f,0.f}, O1B = {0.f,0.f,0.f,0.f}, LsB = {0.f,0.f,0.f,0.f};
    unsigned short* plA = &Pl[wave][0][0];
    unsigned short* plB = &Pl[wave][1][0];
    const int sw  = li & 6;
    const int pw  = li * 32;
    const int wr0 = pw + ((g ^ sw) << 2);          // tile0 chunk g
    const int wr1 = pw + (((4 + g) ^ sw) << 2);    // tile1 chunk 4+g
    const int rdo = pw + (((2 * g) ^ sw) << 2);    // read chunks 2g,2g+1

    const unsigned short* kp0 = kb + (size_t)(jbeg + li) * DH + g * 8;
    const unsigned short* kp1 = kp0 + 16 * DH;
    const unsigned short* vp0 = vb + (size_t)li * NN + jbeg + g * 8;
    const unsigned short* vp1 = vp0 + 16 * NN;

    bf16x8 kf0 = *(const bf16x8*)kp0;
    bf16x8 kf1 = *(const bf16x8*)kp1;
    bf16x8 vf0 = *(const bf16x8*)vp0;
    bf16x8 vf1 = *(const bf16x8*)vp1;

#pragma unroll 2
    for (int it = 0; it < NITER; ++it) {
        kp0 += 32 * DH; kp1 += 32 * DH; vp0 += 32; vp1 += 32;

        f32x4 z = {0.f, 0.f, 0.f, 0.f};
        f32x4 s0A = __builtin_amdgcn_mfma_f32_16x16x32_bf16(kf0, qfA, z, 0, 0, 0);
        f32x4 s0B = __builtin_amdgcn_mfma_f32_16x16x32_bf16(kf0, qfB, z, 0, 0, 0);
        f32x4 s1A = __builtin_amdgcn_mfma_f32_16x16x32_bf16(kf1, qfA, z, 0, 0, 0);
        f32x4 s1B = __builtin_amdgcn_mfma_f32_16x16x32_bf16(kf1, qfB, z, 0, 0, 0);

        // prefetch next-iter fragments (last-iter over-read stays inside ws)
        bf16x8 nk0 = *(const bf16x8*)kp0;
        bf16x8 nk1 = *(const bf16x8*)kp1;
        bf16x8 nv0 = *(const bf16x8*)vp0;
        bf16x8 nv1 = *(const bf16x8*)vp1;

        float p0A[4], p1A[4], p0B[4], p1B[4];
#pragma unroll
        for (int r = 0; r < 4; ++r) {
            p0A[r] = __builtin_amdgcn_exp2f(s0A[r]);
            p1A[r] = __builtin_amdgcn_exp2f(s1A[r]);
            p0B[r] = __builtin_amdgcn_exp2f(s0B[r]);
            p1B[r] = __builtin_amdgcn_exp2f(s1B[r]);
        }

        uint2 wa, wb;
        wa.x = pack_trunc(p0A[0], p0A[1]);  wa.y = pack_trunc(p0A[2], p0A[3]);
        wb.x = pack_trunc(p1A[0], p1A[1]);  wb.y = pack_trunc(p1A[2], p1A[3]);
        *(uint2*)&plA[wr0] = wa;
        *(uint2*)&plA[wr1] = wb;
        wa.x = pack_trunc(p0B[0], p0B[1]);  wa.y = pack_trunc(p0B[2], p0B[3]);
        wb.x = pack_trunc(p1B[0], p1B[1]);  wb.y = pack_trunc(p1B[2], p1B[3]);
        *(uint2*)&plB[wr0] = wa;
        *(uint2*)&plB[wr1] = wb;

        bf16x8 pfA = *(const bf16x8*)&plA[rdo];
        bf16x8 pfB = *(const bf16x8*)&plB[rdo];

        O0A = __builtin_amdgcn_mfma_f32_16x16x32_bf16(vf0,  pfA, O0A, 0, 0, 0);
        O0B = __builtin_amdgcn_mfma_f32_16x16x32_bf16(vf0,  pfB, O0B, 0, 0, 0);
        O1A = __builtin_amdgcn_mfma_f32_16x16x32_bf16(vf1,  pfA, O1A, 0, 0, 0);
        O1B = __builtin_amdgcn_mfma_f32_16x16x32_bf16(vf1,  pfB, O1B, 0, 0, 0);
        LsA = __builtin_amdgcn_mfma_f32_16x16x32_bf16(ones, pfA, LsA, 0, 0, 0);
        LsB = __builtin_amdgcn_mfma_f32_16x16x32_bf16(ones, pfB, LsB, 0, 0, 0);

        kf0 = nk0; kf1 = nk1; vf0 = nv0; vf1 = nv1;
    }

    // epilogue: Op[part][bh][d][n] bf16 (O^T C-layout: col i=li, row d)
    unsigned short* obA = Op + (size_t)part * SEG + (size_t)bh * DH * NN + i0 + li;
    unsigned short* obB = obA + 16;
#pragma unroll
    for (int r = 0; r < 4; ++r) {
        obA[(size_t)(4 * g + r)      * NN] = f2bf(O0A[r]);
        obA[(size_t)(16 + 4 * g + r) * NN] = f2bf(O1A[r]);
        obB[(size_t)(4 * g + r)      * NN] = f2bf(O0B[r]);
        obB[(size_t)(16 + 4 * g + r) * NN] = f2bf(O1B[r]);
    }
    if (g == 0) {
        Lp[(size_t)part * LSEG + (size_t)bh * NN + i0 + li]      = LsA[0];
        Lp[(size_t)part * LSEG + (size_t)bh * NN + i0 + 16 + li] = LsB[0];
    }
}

// ---------------------------------------------------------------------------
// Kernel 3: output projection as bf16 MFMA GEMM.  B staging vectorized:
// 16x b64 coalesced global loads (4 parts x 4 d-rows of 4 n) + register
// transpose + 4x b64 LDS writes per thread/iter (was 64 scalar loads).
// ---------------------------------------------------------------------------
__global__ __launch_bounds__(256) void out_proj_kernel(
    const unsigned short* __restrict__ Op, const float* __restrict__ Lp,
    const float* __restrict__ w, const float* __restrict__ bias,
    float* __restrict__ y)
{
    __shared__ unsigned short As[128 * 40];
    __shared__ unsigned short Bs[128 * 40];
    __shared__ float Linv[4][128];
    const int n0 = blockIdx.x * 128;
    const int o0 = blockIdx.y * 128;
    const int b  = blockIdx.z;
    const int tid  = (int)threadIdx.x;
    const int wave = tid >> 6;
    const int lane = tid & 63;
    const int li   = lane & 15;
    const int g    = lane >> 4;
    const int wm = (wave & 1) * 64;
    const int wn = (wave >> 1) * 64;

    const int aco = (tid & 7) * 4;
    const int aor = tid >> 3;
    const int n4  = (tid & 31) * 4;   // B staging: n base
    const int d4  = (tid >> 5) * 4;   // B staging: d base

    {
        const int h = tid >> 6, nb = tid & 63;
#pragma unroll
        for (int half = 0; half < 2; ++half) {
            const int n = nb + 64 * half;
            float s = 0.f;
#pragma unroll
            for (int p = 0; p < PPARTS; ++p)
                s += Lp[(size_t)p * LSEG + (size_t)(b * NH + h) * NN + n0 + n];
            Linv[h][n] = 1.0f / s;
        }
    }

    f32x4 acc[4][4];
#pragma unroll
    for (int i = 0; i < 4; ++i)
#pragma unroll
        for (int j = 0; j < 4; ++j) acc[i][j] = (f32x4){0.f, 0.f, 0.f, 0.f};

    for (int k0 = 0; k0 < HIDC; k0 += 32) {
        __syncthreads();
#pragma unroll
        for (int r = 0; r < 4; ++r) {
            const int o = aor + 32 * r;
            const float4 wv = *(const float4*)&w[(size_t)(o0 + o) * HIDC + k0 + aco];
            uint2 pk;
            pk.x = (unsigned)f2bf(wv.x) | ((unsigned)f2bf(wv.y) << 16);
            pk.y = (unsigned)f2bf(wv.z) | ((unsigned)f2bf(wv.w) << 16);
            *(uint2*)&As[o * 40 + aco] = pk;
        }
        const int h = k0 >> 5;                      // BK=32 == one head
        const size_t bh = (size_t)(b * NH + h);
        float s[4][4];
#pragma unroll
        for (int dd = 0; dd < 4; ++dd)
#pragma unroll
            for (int j = 0; j < 4; ++j) s[dd][j] = 0.f;
#pragma unroll
        for (int p = 0; p < PPARTS; ++p) {
#pragma unroll
            for (int dd = 0; dd < 4; ++dd) {
                const uint2 u = *(const uint2*)&Op[(size_t)p * SEG
                                  + (bh * DH + d4 + dd) * (size_t)NN + n0 + n4];
                s[dd][0] += bflo(u.x); s[dd][1] += bfhi(u.x);
                s[dd][2] += bflo(u.y); s[dd][3] += bfhi(u.y);
            }
        }
#pragma unroll
        for (int j = 0; j < 4; ++j) {
            const float lv = Linv[h][n4 + j];
            uint2 pk;
            pk.x = (unsigned)f2bf(s[0][j] * lv) | ((unsigned)f2bf(s[1][j] * lv) << 16);
            pk.y = (unsigned)f2bf(s[2][j] * lv) | ((unsigned)f2bf(s[3][j] * lv) << 16);
            *(uint2*)&Bs[(n4 + j) * 40 + d4] = pk;
        }
        __syncthreads();

        bf16x8 af[4], bfr[4];
#pragma unroll
        for (int mt = 0; mt < 4; ++mt)
            af[mt] = *(const bf16x8*)&As[(wm + mt * 16 + li) * 40 + g * 8];
#pragma unroll
        for (int nt = 0; nt < 4; ++nt)
            bfr[nt] = *(const bf16x8*)&Bs[(wn + nt * 16 + li) * 40 + g * 8];
#pragma unroll
        for (int mt = 0; mt < 4; ++mt)
#pragma unroll
            for (int nt = 0; nt < 4; ++nt)
                acc[mt][nt] = __builtin_amdgcn_mfma_f32_16x16x32_bf16(
                    af[mt], bfr[nt], acc[mt][nt], 0, 0, 0);
    }

#pragma unroll
    for (int mt = 0; mt < 4; ++mt) {
        const int ob = o0 + wm + mt * 16 + g * 4;
        const float b0 = bias[ob], b1 = bias[ob + 1], b2 = bias[ob + 2], b3 = bias[ob + 3];
#pragma unroll
        for (int nt = 0; nt < 4; ++nt) {
            const int n = n0 + wn + nt * 16 + li;
            const f32x4 a = acc[mt][nt];
            float* yb = y + ((size_t)(b * CDIM + ob)) * NN + n;
            yb[0]              = a[0] + b0;
            yb[(size_t)NN]     = a[1] + b1;
            yb[(size_t)2 * NN] = a[2] + b2;
            yb[(size_t)3 * NN] = a[3] + b3;
        }
    }
}

// ---------------------------------------------------------------------------
extern "C" void kernel_launch(void* const* d_in, const int* in_sizes, int n_in,
                              void* d_out, int out_size, void* d_ws, size_t ws_size,
                              hipStream_t stream)
{
    (void)in_sizes; (void)n_in; (void)out_size; (void)ws_size;
    const float* x     = (const float*)d_in[0];
    const float* w_qkv = (const float*)d_in[1];
    const float* w_out = (const float*)d_in[2];
    const float* b_out = (const float*)d_in[3];
    float* y = (float*)d_out;

    unsigned short* qt  = (unsigned short*)d_ws;
    unsigned short* kt  = qt + SEG;
    unsigned short* vtT = kt + SEG;
    unsigned short* Op  = vtT + SEG;                     // PPARTS x SEG bf16
    float* Lp = (float*)(Op + (size_t)PPARTS * SEG);     // PPARTS x LSEG fp32

    dim3 g1(NN / 128, OC3 / 128, NB);                    // 18 x 3 x 8
    qkv_proj_kernel<<<g1, 256, 0, stream>>>(x, w_qkv, qt, kt, vtT);

    dim3 g2(2304);                                       // XCD-swizzled 1D grid
    attn_kernel<<<g2, 256, 0, stream>>>(qt, kt, vtT, Op, Lp);

    dim3 g3(NN / 128, CDIM / 128, NB);                   // 18 x 2 x 8
    out_proj_kernel<<<g3, 256, 0, stream>>>(Op, Lp, w_out, b_out, y);
}

// Round 11
// 167.867 us; speedup vs baseline: 1.6660x; 1.0090x over previous
//
#include <hip/hip_runtime.h>
#include <math.h>

#define NB    8
#define CDIM  256
#define NN    2304
#define NH    4
#define DH    32
#define HIDC  128
#define OC3   384
#define SCALE_LOG2E 0.25503524964550864f         // 32^-0.5 * log2(e)
#define SEG   2359296                            // NB*NH*NN*DH
#define LSEG  73728                              // NB*NH*NN
#define PPARTS 4
#define JCHUNK 576                               // NN / PPARTS
#define NITER  18                               // JCHUNK / 32

typedef short  bf16x8 __attribute__((ext_vector_type(8)));
typedef float  f32x4  __attribute__((ext_vector_type(4)));

__device__ __forceinline__ unsigned short f2bf(float f) {
    union { float f; unsigned u; } a; a.f = f;
    unsigned r = a.u + 0x7fffu + ((a.u >> 16) & 1u);   // RNE
    return (unsigned short)(r >> 16);
}

__device__ __forceinline__ unsigned pack_trunc(float lo, float hi) {
    union { float f; unsigned u; } a, b; a.f = lo; b.f = hi;
    return (b.u & 0xFFFF0000u) | (a.u >> 16);          // bf16x2, truncated
}

__device__ __forceinline__ float bflo(unsigned u) {
    union { unsigned u; float f; } c; c.u = u << 16; return c.f;
}
__device__ __forceinline__ float bfhi(unsigned u) {
    union { unsigned u; float f; } c; c.u = u & 0xFFFF0000u; return c.f;
}

// ---------------------------------------------------------------------------
// Kernel 1: QKV projection, 128x128-tile bf16 MFMA GEMM (R9-proven indexing)
// + register prefetch hoist: next K-step's global loads issue right after the
// staging barrier so their latency hides under the 16 MFMAs (this kernel runs
// at ~1.7 blocks/CU, so intra-block overlap is the only latency cover).
//   qt,kt: [bh][n][32] bf16 (q pre-scaled into exp2 domain)
//   vtT:   [bh][32][n] bf16
// ---------------------------------------------------------------------------
__global__ __launch_bounds__(256) void qkv_proj_kernel(
    const float* __restrict__ x, const float* __restrict__ w,
    unsigned short* __restrict__ qt, unsigned short* __restrict__ kt,
    unsigned short* __restrict__ vtT)
{
    __shared__ unsigned short As[128 * 40];
    __shared__ unsigned short Bs[128 * 40];
    const int n0 = blockIdx.x * 128;
    const int o0 = blockIdx.y * 128;
    const int b  = blockIdx.z;
    const int tid  = (int)threadIdx.x;
    const int wave = tid >> 6;
    const int lane = tid & 63;
    const int li   = lane & 15;
    const int g    = lane >> 4;
    const int wm = (wave & 1) * 64;
    const int wn = (wave >> 1) * 64;
    const float* xb = x + (size_t)b * CDIM * NN;

    const int aco = (tid & 7) * 4;    // A staging: c offset
    const int aor = tid >> 3;         // A staging: o row 0..31
    const int n4  = (tid & 31) * 4;   // B staging: n base
    const int c4  = (tid >> 5) * 4;   // B staging: c base

    f32x4 acc[4][4];
#pragma unroll
    for (int i = 0; i < 4; ++i)
#pragma unroll
        for (int j = 0; j < 4; ++j) acc[i][j] = (f32x4){0.f, 0.f, 0.f, 0.f};

    float4 wv[4], xv[4];
#pragma unroll
    for (int r = 0; r < 4; ++r)
        wv[r] = *(const float4*)&w[(size_t)(o0 + aor + 32 * r) * CDIM + aco];
#pragma unroll
    for (int dd = 0; dd < 4; ++dd)
        xv[dd] = *(const float4*)&xb[(size_t)(c4 + dd) * NN + n0 + n4];

    for (int k0 = 0; k0 < CDIM; k0 += 32) {
        __syncthreads();
#pragma unroll
        for (int r = 0; r < 4; ++r) {
            uint2 pk;
            pk.x = (unsigned)f2bf(wv[r].x) | ((unsigned)f2bf(wv[r].y) << 16);
            pk.y = (unsigned)f2bf(wv[r].z) | ((unsigned)f2bf(wv[r].w) << 16);
            *(uint2*)&As[(aor + 32 * r) * 40 + aco] = pk;
        }
#pragma unroll
        for (int j = 0; j < 4; ++j) {
            uint2 pk;
            pk.x = (unsigned)f2bf(((const float*)&xv[0])[j])
                 | ((unsigned)f2bf(((const float*)&xv[1])[j]) << 16);
            pk.y = (unsigned)f2bf(((const float*)&xv[2])[j])
                 | ((unsigned)f2bf(((const float*)&xv[3])[j]) << 16);
            *(uint2*)&Bs[(n4 + j) * 40 + c4] = pk;
        }
        __syncthreads();

        // prefetch next K-step (clamped address on last iter; values dead)
        const int kn = (k0 + 32 < CDIM) ? (k0 + 32) : k0;
#pragma unroll
        for (int r = 0; r < 4; ++r)
            wv[r] = *(const float4*)&w[(size_t)(o0 + aor + 32 * r) * CDIM + kn + aco];
#pragma unroll
        for (int dd = 0; dd < 4; ++dd)
            xv[dd] = *(const float4*)&xb[(size_t)(kn + c4 + dd) * NN + n0 + n4];

        bf16x8 af[4], bfr[4];
#pragma unroll
        for (int mt = 0; mt < 4; ++mt)
            af[mt] = *(const bf16x8*)&As[(wm + mt * 16 + li) * 40 + g * 8];
#pragma unroll
        for (int nt = 0; nt < 4; ++nt)
            bfr[nt] = *(const bf16x8*)&Bs[(wn + nt * 16 + li) * 40 + g * 8];
#pragma unroll
        for (int mt = 0; mt < 4; ++mt)
#pragma unroll
            for (int nt = 0; nt < 4; ++nt)
                acc[mt][nt] = __builtin_amdgcn_mfma_f32_16x16x32_bf16(
                    af[mt], bfr[nt], acc[mt][nt], 0, 0, 0);
    }

    const int sel = blockIdx.y;
    if (sel < 2) {
        unsigned short* dst = (sel == 0) ? qt : kt;
        const float mul = (sel == 0) ? SCALE_LOG2E : 1.0f;
#pragma unroll
        for (int mt = 0; mt < 4; ++mt) {
            const int ob = o0 + wm + mt * 16 + g * 4;
            const int d0 = ob & 31;
            const int h  = (ob & 127) >> 5;
            const size_t bh = (size_t)(b * NH + h);
#pragma unroll
            for (int nt = 0; nt < 4; ++nt) {
                const int n = n0 + wn + nt * 16 + li;
                const f32x4 a = acc[mt][nt];
                uint2 pk;
                pk.x = (unsigned)f2bf(a[0] * mul) | ((unsigned)f2bf(a[1] * mul) << 16);
                pk.y = (unsigned)f2bf(a[2] * mul) | ((unsigned)f2bf(a[3] * mul) << 16);
                *(uint2*)&dst[(bh * NN + n) * DH + d0] = pk;
            }
        }
    } else {
#pragma unroll
        for (int mt = 0; mt < 4; ++mt) {
            const int ob = o0 + wm + mt * 16 + g * 4;
            const int d0 = ob & 31;
            const int h  = (ob & 127) >> 5;
            const size_t bh = (size_t)(b * NH + h);
#pragma unroll
            for (int nt = 0; nt < 4; ++nt) {
                const int n = n0 + wn + nt * 16 + li;
                const f32x4 a = acc[mt][nt];
#pragma unroll
                for (int r = 0; r < 4; ++r)
                    vtT[(bh * DH + d0 + r) * (size_t)NN + n] = f2bf(a[r]);
            }
        }
    }
}

// ---------------------------------------------------------------------------
// Kernel 2: MFMA flash attention — R9 verbatim (75.5 us proven).
// XOR-swizzled LDS transpose, 32 queries/wave, XCD-swizzled grid, j-split.
// ---------------------------------------------------------------------------
__global__ __launch_bounds__(256) void attn_kernel(
    const unsigned short* __restrict__ qt, const unsigned short* __restrict__ kt,
    const unsigned short* __restrict__ vtT, unsigned short* __restrict__ Op,
    float* __restrict__ Lp)
{
    __shared__ unsigned short Pl[4][2][16 * 32];
    const int Lb  = (int)blockIdx.x;          // 0..2303
    const int xcd = Lb & 7;
    const int t   = Lb >> 3;                  // 0..287
    const int ib  = t % 18;                   // i-block
    const int grp = (t / 18) * 8 + xcd;       // 0..127, XCD-resident group
    const int bh  = grp >> 2;
    const int part = grp & 3;
    const int jbeg = part * JCHUNK;

    const int tid  = (int)threadIdx.x;
    const int wave = tid >> 6;
    const int lane = tid & 63;
    const int li   = lane & 15;
    const int g    = lane >> 4;
    const int i0   = ib * 128 + wave * 32;

    const unsigned short* qb = qt  + (size_t)bh * NN * DH;
    const unsigned short* kb = kt  + (size_t)bh * NN * DH;
    const unsigned short* vb = vtT + (size_t)bh * DH * NN;

    bf16x8 qfA = *(const bf16x8*)(qb + (size_t)(i0 + li) * DH + g * 8);
    bf16x8 qfB = *(const bf16x8*)(qb + (size_t)(i0 + 16 + li) * DH + g * 8);

    bf16x8 ones;
#pragma unroll
    for (int r = 0; r < 8; ++r) ones[r] = (short)0x3F80;

    f32x4 O0A = {0.f,0.f,0.f,0.f}, O1A = {0.f,0.f,0.f,0.f}, LsA = {0.f,0.f,0.f,0.f};
    f32x4 O0B = {0.f,0.f,0.f,0.f}, O1B = {0.f,0.f,0.f,0.f}, LsB = {0.f,0.f,0.f,0.f};
    unsigned short* plA = &Pl[wave][0][0];
    unsigned short* plB = &Pl[wave][1][0];
    const int sw  = li & 6;
    const int pw  = li * 32;
    const int wr0 = pw + ((g ^ sw) << 2);          // tile0 chunk g
    const int wr1 = pw + (((4 + g) ^ sw) << 2);    // tile1 chunk 4+g
    const int rdo = pw + (((2 * g) ^ sw) << 2);    // read chunks 2g,2g+1

    const unsigned short* kp0 = kb + (size_t)(jbeg + li) * DH + g * 8;
    const unsigned short* kp1 = kp0 + 16 * DH;
    const unsigned short* vp0 = vb + (size_t)li * NN + jbeg + g * 8;
    const unsigned short* vp1 = vp0 + 16 * NN;

    bf16x8 kf0 = *(const bf16x8*)kp0;
    bf16x8 kf1 = *(const bf16x8*)kp1;
    bf16x8 vf0 = *(const bf16x8*)vp0;
    bf16x8 vf1 = *(const bf16x8*)vp1;

#pragma unroll 2
    for (int it = 0; it < NITER; ++it) {
        kp0 += 32 * DH; kp1 += 32 * DH; vp0 += 32; vp1 += 32;

        f32x4 z = {0.f, 0.f, 0.f, 0.f};
        f32x4 s0A = __builtin_amdgcn_mfma_f32_16x16x32_bf16(kf0, qfA, z, 0, 0, 0);
        f32x4 s0B = __builtin_amdgcn_mfma_f32_16x16x32_bf16(kf0, qfB, z, 0, 0, 0);
        f32x4 s1A = __builtin_amdgcn_mfma_f32_16x16x32_bf16(kf1, qfA, z, 0, 0, 0);
        f32x4 s1B = __builtin_amdgcn_mfma_f32_16x16x32_bf16(kf1, qfB, z, 0, 0, 0);

        // prefetch next-iter fragments (last-iter over-read stays inside ws)
        bf16x8 nk0 = *(const bf16x8*)kp0;
        bf16x8 nk1 = *(const bf16x8*)kp1;
        bf16x8 nv0 = *(const bf16x8*)vp0;
        bf16x8 nv1 = *(const bf16x8*)vp1;

        float p0A[4], p1A[4], p0B[4], p1B[4];
#pragma unroll
        for (int r = 0; r < 4; ++r) {
            p0A[r] = __builtin_amdgcn_exp2f(s0A[r]);
            p1A[r] = __builtin_amdgcn_exp2f(s1A[r]);
            p0B[r] = __builtin_amdgcn_exp2f(s0B[r]);
            p1B[r] = __builtin_amdgcn_exp2f(s1B[r]);
        }

        uint2 wa, wb;
        wa.x = pack_trunc(p0A[0], p0A[1]);  wa.y = pack_trunc(p0A[2], p0A[3]);
        wb.x = pack_trunc(p1A[0], p1A[1]);  wb.y = pack_trunc(p1A[2], p1A[3]);
        *(uint2*)&plA[wr0] = wa;
        *(uint2*)&plA[wr1] = wb;
        wa.x = pack_trunc(p0B[0], p0B[1]);  wa.y = pack_trunc(p0B[2], p0B[3]);
        wb.x = pack_trunc(p1B[0], p1B[1]);  wb.y = pack_trunc(p1B[2], p1B[3]);
        *(uint2*)&plB[wr0] = wa;
        *(uint2*)&plB[wr1] = wb;

        bf16x8 pfA = *(const bf16x8*)&plA[rdo];
        bf16x8 pfB = *(const bf16x8*)&plB[rdo];

        O0A = __builtin_amdgcn_mfma_f32_16x16x32_bf16(vf0,  pfA, O0A, 0, 0, 0);
        O0B = __builtin_amdgcn_mfma_f32_16x16x32_bf16(vf0,  pfB, O0B, 0, 0, 0);
        O1A = __builtin_amdgcn_mfma_f32_16x16x32_bf16(vf1,  pfA, O1A, 0, 0, 0);
        O1B = __builtin_amdgcn_mfma_f32_16x16x32_bf16(vf1,  pfB, O1B, 0, 0, 0);
        LsA = __builtin_amdgcn_mfma_f32_16x16x32_bf16(ones, pfA, LsA, 0, 0, 0);
        LsB = __builtin_amdgcn_mfma_f32_16x16x32_bf16(ones, pfB, LsB, 0, 0, 0);

        kf0 = nk0; kf1 = nk1; vf0 = nv0; vf1 = nv1;
    }

    // epilogue: Op[part][bh][d][n] bf16 (O^T C-layout: col i=li, row d)
    unsigned short* obA = Op + (size_t)part * SEG + (size_t)bh * DH * NN + i0 + li;
    unsigned short* obB = obA + 16;
#pragma unroll
    for (int r = 0; r < 4; ++r) {
        obA[(size_t)(4 * g + r)      * NN] = f2bf(O0A[r]);
        obA[(size_t)(16 + 4 * g + r) * NN] = f2bf(O1A[r]);
        obB[(size_t)(4 * g + r)      * NN] = f2bf(O0B[r]);
        obB[(size_t)(16 + 4 * g + r) * NN] = f2bf(O1B[r]);
    }
    if (g == 0) {
        Lp[(size_t)part * LSEG + (size_t)bh * NN + i0 + li]      = LsA[0];
        Lp[(size_t)part * LSEG + (size_t)bh * NN + i0 + 16 + li] = LsB[0];
    }
}

// ---------------------------------------------------------------------------
// Kernel 3: output projection, 128x128-tile bf16 MFMA GEMM (R9-proven
// indexing) + register prefetch hoist (same pattern as kernel 1).  B staging
// folds the 4-way bf16 partial-O reduction and the 1/l normalization.
// ---------------------------------------------------------------------------
__global__ __launch_bounds__(256) void out_proj_kernel(
    const unsigned short* __restrict__ Op, const float* __restrict__ Lp,
    const float* __restrict__ w, const float* __restrict__ bias,
    float* __restrict__ y)
{
    __shared__ unsigned short As[128 * 40];
    __shared__ unsigned short Bs[128 * 40];
    __shared__ float Linv[4][128];
    const int n0 = blockIdx.x * 128;
    const int o0 = blockIdx.y * 128;
    const int b  = blockIdx.z;
    const int tid  = (int)threadIdx.x;
    const int wave = tid >> 6;
    const int lane = tid & 63;
    const int li   = lane & 15;
    const int g    = lane >> 4;
    const int wm = (wave & 1) * 64;
    const int wn = (wave >> 1) * 64;

    const int aco = (tid & 7) * 4;
    const int aor = tid >> 3;
    const int n4  = (tid & 31) * 4;   // B staging: n base
    const int d4  = (tid >> 5) * 4;   // B staging: d base

    {
        const int h = tid >> 6, nb = tid & 63;
#pragma unroll
        for (int half = 0; half < 2; ++half) {
            const int n = nb + 64 * half;
            float s = 0.f;
#pragma unroll
            for (int p = 0; p < PPARTS; ++p)
                s += Lp[(size_t)p * LSEG + (size_t)(b * NH + h) * NN + n0 + n];
            Linv[h][n] = 1.0f / s;
        }
    }

    f32x4 acc[4][4];
#pragma unroll
    for (int i = 0; i < 4; ++i)
#pragma unroll
        for (int j = 0; j < 4; ++j) acc[i][j] = (f32x4){0.f, 0.f, 0.f, 0.f};

    float4 wv[4];
    uint2  ov[PPARTS][4];
#pragma unroll
    for (int r = 0; r < 4; ++r)
        wv[r] = *(const float4*)&w[(size_t)(o0 + aor + 32 * r) * HIDC + aco];
    {
        const size_t bh0 = (size_t)(b * NH);
#pragma unroll
        for (int p = 0; p < PPARTS; ++p)
#pragma unroll
            for (int dd = 0; dd < 4; ++dd)
                ov[p][dd] = *(const uint2*)&Op[(size_t)p * SEG
                              + (bh0 * DH + d4 + dd) * (size_t)NN + n0 + n4];
    }

    for (int k0 = 0; k0 < HIDC; k0 += 32) {
        __syncthreads();
#pragma unroll
        for (int r = 0; r < 4; ++r) {
            uint2 pk;
            pk.x = (unsigned)f2bf(wv[r].x) | ((unsigned)f2bf(wv[r].y) << 16);
            pk.y = (unsigned)f2bf(wv[r].z) | ((unsigned)f2bf(wv[r].w) << 16);
            *(uint2*)&As[(aor + 32 * r) * 40 + aco] = pk;
        }
        const int h = k0 >> 5;                      // BK=32 == one head
        {
            float s[4][4];
#pragma unroll
            for (int dd = 0; dd < 4; ++dd)
#pragma unroll
                for (int j = 0; j < 4; ++j) s[dd][j] = 0.f;
#pragma unroll
            for (int p = 0; p < PPARTS; ++p) {
#pragma unroll
                for (int dd = 0; dd < 4; ++dd) {
                    const uint2 u = ov[p][dd];
                    s[dd][0] += bflo(u.x); s[dd][1] += bfhi(u.x);
                    s[dd][2] += bflo(u.y); s[dd][3] += bfhi(u.y);
                }
            }
#pragma unroll
            for (int j = 0; j < 4; ++j) {
                const float lv = Linv[h][n4 + j];
                uint2 pk;
                pk.x = (unsigned)f2bf(s[0][j] * lv) | ((unsigned)f2bf(s[1][j] * lv) << 16);
                pk.y = (unsigned)f2bf(s[2][j] * lv) | ((unsigned)f2bf(s[3][j] * lv) << 16);
                *(uint2*)&Bs[(n4 + j) * 40 + d4] = pk;
            }
        }
        __syncthreads();

        // prefetch next K-step (clamped on last iter; values dead)
        const int kn = (k0 + 32 < HIDC) ? (k0 + 32) : k0;
        const size_t bhn = (size_t)(b * NH + (kn >> 5));
#pragma unroll
        for (int r = 0; r < 4; ++r)
            wv[r] = *(const float4*)&w[(size_t)(o0 + aor + 32 * r) * HIDC + kn + aco];
#pragma unroll
        for (int p = 0; p < PPARTS; ++p)
#pragma unroll
            for (int dd = 0; dd < 4; ++dd)
                ov[p][dd] = *(const uint2*)&Op[(size_t)p * SEG
                              + (bhn * DH + d4 + dd) * (size_t)NN + n0 + n4];

        bf16x8 af[4], bfr[4];
#pragma unroll
        for (int mt = 0; mt < 4; ++mt)
            af[mt] = *(const bf16x8*)&As[(wm + mt * 16 + li) * 40 + g * 8];
#pragma unroll
        for (int nt = 0; nt < 4; ++nt)
            bfr[nt] = *(const bf16x8*)&Bs[(wn + nt * 16 + li) * 40 + g * 8];
#pragma unroll
        for (int mt = 0; mt < 4; ++mt)
#pragma unroll
            for (int nt = 0; nt < 4; ++nt)
                acc[mt][nt] = __builtin_amdgcn_mfma_f32_16x16x32_bf16(
                    af[mt], bfr[nt], acc[mt][nt], 0, 0, 0);
    }

#pragma unroll
    for (int mt = 0; mt < 4; ++mt) {
        const int ob = o0 + wm + mt * 16 + g * 4;
        const float b0 = bias[ob], b1 = bias[ob + 1], b2 = bias[ob + 2], b3 = bias[ob + 3];
#pragma unroll
        for (int nt = 0; nt < 4; ++nt) {
            const int n = n0 + wn + nt * 16 + li;
            const f32x4 a = acc[mt][nt];
            float* yb = y + ((size_t)(b * CDIM + ob)) * NN + n;
            yb[0]              = a[0] + b0;
            yb[(size_t)NN]     = a[1] + b1;
            yb[(size_t)2 * NN] = a[2] + b2;
            yb[(size_t)3 * NN] = a[3] + b3;
        }
    }
}

// ---------------------------------------------------------------------------
extern "C" void kernel_launch(void* const* d_in, const int* in_sizes, int n_in,
                              void* d_out, int out_size, void* d_ws, size_t ws_size,
                              hipStream_t stream)
{
    (void)in_sizes; (void)n_in; (void)out_size; (void)ws_size;
    const float* x     = (const float*)d_in[0];
    const float* w_qkv = (const float*)d_in[1];
    const float* w_out = (const float*)d_in[2];
    const float* b_out = (const float*)d_in[3];
    float* y = (float*)d_out;

    unsigned short* qt  = (unsigned short*)d_ws;
    unsigned short* kt  = qt + SEG;
    unsigned short* vtT = kt + SEG;
    unsigned short* Op  = vtT + SEG;                     // PPARTS x SEG bf16
    float* Lp = (float*)(Op + (size_t)PPARTS * SEG);     // PPARTS x LSEG fp32

    dim3 g1(NN / 128, OC3 / 128, NB);                    // 18 x 3 x 8 = 432
    qkv_proj_kernel<<<g1, 256, 0, stream>>>(x, w_qkv, qt, kt, vtT);

    dim3 g2(2304);                                       // XCD-swizzled 1D grid
    attn_kernel<<<g2, 256, 0, stream>>>(qt, kt, vtT, Op, Lp);

    dim3 g3(NN / 128, CDIM / 128, NB);                   // 18 x 2 x 8 = 288
    out_proj_kernel<<<g3, 256, 0, stream>>>(Op, Lp, w_out, b_out, y);
}

// Round 12
// 163.815 us; speedup vs baseline: 1.7073x; 1.0247x over previous
//
#include <hip/hip_runtime.h>
#include <math.h>

#define NB    8
#define CDIM  256
#define NN    2304
#define NH    4
#define DH    32
#define HIDC  128
#define OC3   384
#define SCALE_LOG2E 0.25503524964550864f         // 32^-0.5 * log2(e)
#define SEG   2359296                            // NB*NH*NN*DH
#define LSEG  73728                              // NB*NH*NN
#define PPARTS 4
#define JCHUNK 576                               // NN / PPARTS
#define NITER  18                               // JCHUNK / 32

typedef short  bf16x8 __attribute__((ext_vector_type(8)));
typedef float  f32x4  __attribute__((ext_vector_type(4)));

__device__ __forceinline__ unsigned short f2bf(float f) {
    union { float f; unsigned u; } a; a.f = f;
    unsigned r = a.u + 0x7fffu + ((a.u >> 16) & 1u);   // RNE
    return (unsigned short)(r >> 16);
}

__device__ __forceinline__ unsigned pack_trunc(float lo, float hi) {
    union { float f; unsigned u; } a, b; a.f = lo; b.f = hi;
    return (b.u & 0xFFFF0000u) | (a.u >> 16);          // bf16x2, truncated
}

__device__ __forceinline__ float bflo(unsigned u) {
    union { unsigned u; float f; } c; c.u = u << 16; return c.f;
}
__device__ __forceinline__ float bfhi(unsigned u) {
    union { unsigned u; float f; } c; c.u = u & 0xFFFF0000u; return c.f;
}

// ---------------------------------------------------------------------------
// Kernel 1: QKV projection, 128x128-tile bf16 MFMA GEMM (R9/R11-proven
// internals).  1D grid, XCD-grouped: the 3 sel-blocks (q,k,v) of one
// (n-tile, b) are consecutive on ONE XCD, so the shared 128 KB x-tile is
// read once from HBM and twice from that XCD's L2 (was 3x HBM/L3,
// cross-XCD).  Register prefetch hoist kept from R11.
// ---------------------------------------------------------------------------
__global__ __launch_bounds__(256) void qkv_proj_kernel(
    const float* __restrict__ x, const float* __restrict__ w,
    unsigned short* __restrict__ qt, unsigned short* __restrict__ kt,
    unsigned short* __restrict__ vtT)
{
    __shared__ unsigned short As[128 * 40];
    __shared__ unsigned short Bs[128 * 40];
    // XCD-grouped decode: Lb in [0,432)
    const int Lb   = (int)blockIdx.x;
    const int xcd  = Lb & 7;
    const int t    = Lb >> 3;            // 0..53 (per-XCD sequence)
    const int sel  = t % 3;              // q/k/v varies fastest within XCD
    const int gl   = t / 3;              // 0..17
    const int group = gl * 8 + xcd;      // 0..143
    const int nb   = group % 18;
    const int b    = group / 18;
    const int n0 = nb * 128;
    const int o0 = sel * 128;

    const int tid  = (int)threadIdx.x;
    const int wave = tid >> 6;
    const int lane = tid & 63;
    const int li   = lane & 15;
    const int g    = lane >> 4;
    const int wm = (wave & 1) * 64;
    const int wn = (wave >> 1) * 64;
    const float* xb = x + (size_t)b * CDIM * NN;

    const int aco = (tid & 7) * 4;    // A staging: c offset
    const int aor = tid >> 3;         // A staging: o row 0..31
    const int n4  = (tid & 31) * 4;   // B staging: n base
    const int c4  = (tid >> 5) * 4;   // B staging: c base

    f32x4 acc[4][4];
#pragma unroll
    for (int i = 0; i < 4; ++i)
#pragma unroll
        for (int j = 0; j < 4; ++j) acc[i][j] = (f32x4){0.f, 0.f, 0.f, 0.f};

    float4 wv[4], xv[4];
#pragma unroll
    for (int r = 0; r < 4; ++r)
        wv[r] = *(const float4*)&w[(size_t)(o0 + aor + 32 * r) * CDIM + aco];
#pragma unroll
    for (int dd = 0; dd < 4; ++dd)
        xv[dd] = *(const float4*)&xb[(size_t)(c4 + dd) * NN + n0 + n4];

    for (int k0 = 0; k0 < CDIM; k0 += 32) {
        __syncthreads();
#pragma unroll
        for (int r = 0; r < 4; ++r) {
            uint2 pk;
            pk.x = (unsigned)f2bf(wv[r].x) | ((unsigned)f2bf(wv[r].y) << 16);
            pk.y = (unsigned)f2bf(wv[r].z) | ((unsigned)f2bf(wv[r].w) << 16);
            *(uint2*)&As[(aor + 32 * r) * 40 + aco] = pk;
        }
#pragma unroll
        for (int j = 0; j < 4; ++j) {
            uint2 pk;
            pk.x = (unsigned)f2bf(((const float*)&xv[0])[j])
                 | ((unsigned)f2bf(((const float*)&xv[1])[j]) << 16);
            pk.y = (unsigned)f2bf(((const float*)&xv[2])[j])
                 | ((unsigned)f2bf(((const float*)&xv[3])[j]) << 16);
            *(uint2*)&Bs[(n4 + j) * 40 + c4] = pk;
        }
        __syncthreads();

        // prefetch next K-step (clamped address on last iter; values dead)
        const int kn = (k0 + 32 < CDIM) ? (k0 + 32) : k0;
#pragma unroll
        for (int r = 0; r < 4; ++r)
            wv[r] = *(const float4*)&w[(size_t)(o0 + aor + 32 * r) * CDIM + kn + aco];
#pragma unroll
        for (int dd = 0; dd < 4; ++dd)
            xv[dd] = *(const float4*)&xb[(size_t)(kn + c4 + dd) * NN + n0 + n4];

        bf16x8 af[4], bfr[4];
#pragma unroll
        for (int mt = 0; mt < 4; ++mt)
            af[mt] = *(const bf16x8*)&As[(wm + mt * 16 + li) * 40 + g * 8];
#pragma unroll
        for (int nt = 0; nt < 4; ++nt)
            bfr[nt] = *(const bf16x8*)&Bs[(wn + nt * 16 + li) * 40 + g * 8];
#pragma unroll
        for (int mt = 0; mt < 4; ++mt)
#pragma unroll
            for (int nt = 0; nt < 4; ++nt)
                acc[mt][nt] = __builtin_amdgcn_mfma_f32_16x16x32_bf16(
                    af[mt], bfr[nt], acc[mt][nt], 0, 0, 0);
    }

    if (sel < 2) {
        unsigned short* dst = (sel == 0) ? qt : kt;
        const float mul = (sel == 0) ? SCALE_LOG2E : 1.0f;
#pragma unroll
        for (int mt = 0; mt < 4; ++mt) {
            const int ob = o0 + wm + mt * 16 + g * 4;
            const int d0 = ob & 31;
            const int h  = (ob & 127) >> 5;
            const size_t bh = (size_t)(b * NH + h);
#pragma unroll
            for (int nt = 0; nt < 4; ++nt) {
                const int n = n0 + wn + nt * 16 + li;
                const f32x4 a = acc[mt][nt];
                uint2 pk;
                pk.x = (unsigned)f2bf(a[0] * mul) | ((unsigned)f2bf(a[1] * mul) << 16);
                pk.y = (unsigned)f2bf(a[2] * mul) | ((unsigned)f2bf(a[3] * mul) << 16);
                *(uint2*)&dst[(bh * NN + n) * DH + d0] = pk;
            }
        }
    } else {
#pragma unroll
        for (int mt = 0; mt < 4; ++mt) {
            const int ob = o0 + wm + mt * 16 + g * 4;
            const int d0 = ob & 31;
            const int h  = (ob & 127) >> 5;
            const size_t bh = (size_t)(b * NH + h);
#pragma unroll
            for (int nt = 0; nt < 4; ++nt) {
                const int n = n0 + wn + nt * 16 + li;
                const f32x4 a = acc[mt][nt];
#pragma unroll
                for (int r = 0; r < 4; ++r)
                    vtT[(bh * DH + d0 + r) * (size_t)NN + n] = f2bf(a[r]);
            }
        }
    }
}

// ---------------------------------------------------------------------------
// Kernel 2: MFMA flash attention — R9 structure; prefetch WITHOUT register
// rotation: kf0/kf1 reload directly after their last use (the S-MFMAs),
// vf0/vf1 after the PV-MFMAs.  Same addresses/values, ~32 fewer v_mov/iter.
// ---------------------------------------------------------------------------
__global__ __launch_bounds__(256) void attn_kernel(
    const unsigned short* __restrict__ qt, const unsigned short* __restrict__ kt,
    const unsigned short* __restrict__ vtT, unsigned short* __restrict__ Op,
    float* __restrict__ Lp)
{
    __shared__ unsigned short Pl[4][2][16 * 32];
    const int Lb  = (int)blockIdx.x;          // 0..2303
    const int xcd = Lb & 7;
    const int t   = Lb >> 3;                  // 0..287
    const int ib  = t % 18;                   // i-block
    const int grp = (t / 18) * 8 + xcd;       // 0..127, XCD-resident group
    const int bh  = grp >> 2;
    const int part = grp & 3;
    const int jbeg = part * JCHUNK;

    const int tid  = (int)threadIdx.x;
    const int wave = tid >> 6;
    const int lane = tid & 63;
    const int li   = lane & 15;
    const int g    = lane >> 4;
    const int i0   = ib * 128 + wave * 32;

    const unsigned short* qb = qt  + (size_t)bh * NN * DH;
    const unsigned short* kb = kt  + (size_t)bh * NN * DH;
    const unsigned short* vb = vtT + (size_t)bh * DH * NN;

    bf16x8 qfA = *(const bf16x8*)(qb + (size_t)(i0 + li) * DH + g * 8);
    bf16x8 qfB = *(const bf16x8*)(qb + (size_t)(i0 + 16 + li) * DH + g * 8);

    bf16x8 ones;
#pragma unroll
    for (int r = 0; r < 8; ++r) ones[r] = (short)0x3F80;

    f32x4 O0A = {0.f,0.f,0.f,0.f}, O1A = {0.f,0.f,0.f,0.f}, LsA = {0.f,0.f,0.f,0.f};
    f32x4 O0B = {0.f,0.f,0.f,0.f}, O1B = {0.f,0.f,0.f,0.f}, LsB = {0.f,0.f,0.f,0.f};
    unsigned short* plA = &Pl[wave][0][0];
    unsigned short* plB = &Pl[wave][1][0];
    const int sw  = li & 6;
    const int pw  = li * 32;
    const int wr0 = pw + ((g ^ sw) << 2);          // tile0 chunk g
    const int wr1 = pw + (((4 + g) ^ sw) << 2);    // tile1 chunk 4+g
    const int rdo = pw + (((2 * g) ^ sw) << 2);    // read chunks 2g,2g+1

    const unsigned short* kp0 = kb + (size_t)(jbeg + li) * DH + g * 8;
    const unsigned short* kp1 = kp0 + 16 * DH;
    const unsigned short* vp0 = vb + (size_t)li * NN + jbeg + g * 8;
    const unsigned short* vp1 = vp0 + 16 * NN;

    bf16x8 kf0 = *(const bf16x8*)kp0;
    bf16x8 kf1 = *(const bf16x8*)kp1;
    bf16x8 vf0 = *(const bf16x8*)vp0;
    bf16x8 vf1 = *(const bf16x8*)vp1;

#pragma unroll 2
    for (int it = 0; it < NITER; ++it) {
        f32x4 z = {0.f, 0.f, 0.f, 0.f};
        f32x4 s0A = __builtin_amdgcn_mfma_f32_16x16x32_bf16(kf0, qfA, z, 0, 0, 0);
        f32x4 s0B = __builtin_amdgcn_mfma_f32_16x16x32_bf16(kf0, qfB, z, 0, 0, 0);
        f32x4 s1A = __builtin_amdgcn_mfma_f32_16x16x32_bf16(kf1, qfA, z, 0, 0, 0);
        f32x4 s1B = __builtin_amdgcn_mfma_f32_16x16x32_bf16(kf1, qfB, z, 0, 0, 0);

        // kf dead -> reload in place for next iter (last-iter over-read
        // stays inside the workspace)
        kp0 += 32 * DH; kp1 += 32 * DH;
        kf0 = *(const bf16x8*)kp0;
        kf1 = *(const bf16x8*)kp1;

        float p0A[4], p1A[4], p0B[4], p1B[4];
#pragma unroll
        for (int r = 0; r < 4; ++r) {
            p0A[r] = __builtin_amdgcn_exp2f(s0A[r]);
            p1A[r] = __builtin_amdgcn_exp2f(s1A[r]);
            p0B[r] = __builtin_amdgcn_exp2f(s0B[r]);
            p1B[r] = __builtin_amdgcn_exp2f(s1B[r]);
        }

        uint2 wa, wb;
        wa.x = pack_trunc(p0A[0], p0A[1]);  wa.y = pack_trunc(p0A[2], p0A[3]);
        wb.x = pack_trunc(p1A[0], p1A[1]);  wb.y = pack_trunc(p1A[2], p1A[3]);
        *(uint2*)&plA[wr0] = wa;
        *(uint2*)&plA[wr1] = wb;
        wa.x = pack_trunc(p0B[0], p0B[1]);  wa.y = pack_trunc(p0B[2], p0B[3]);
        wb.x = pack_trunc(p1B[0], p1B[1]);  wb.y = pack_trunc(p1B[2], p1B[3]);
        *(uint2*)&plB[wr0] = wa;
        *(uint2*)&plB[wr1] = wb;

        bf16x8 pfA = *(const bf16x8*)&plA[rdo];
        bf16x8 pfB = *(const bf16x8*)&plB[rdo];

        O0A = __builtin_amdgcn_mfma_f32_16x16x32_bf16(vf0,  pfA, O0A, 0, 0, 0);
        O0B = __builtin_amdgcn_mfma_f32_16x16x32_bf16(vf0,  pfB, O0B, 0, 0, 0);
        O1A = __builtin_amdgcn_mfma_f32_16x16x32_bf16(vf1,  pfA, O1A, 0, 0, 0);
        O1B = __builtin_amdgcn_mfma_f32_16x16x32_bf16(vf1,  pfB, O1B, 0, 0, 0);
        LsA = __builtin_amdgcn_mfma_f32_16x16x32_bf16(ones, pfA, LsA, 0, 0, 0);
        LsB = __builtin_amdgcn_mfma_f32_16x16x32_bf16(ones, pfB, LsB, 0, 0, 0);

        // vf dead -> reload in place for next iter
        vp0 += 32; vp1 += 32;
        vf0 = *(const bf16x8*)vp0;
        vf1 = *(const bf16x8*)vp1;
    }

    // epilogue: Op[part][bh][d][n] bf16 (O^T C-layout: col i=li, row d)
    unsigned short* obA = Op + (size_t)part * SEG + (size_t)bh * DH * NN + i0 + li;
    unsigned short* obB = obA + 16;
#pragma unroll
    for (int r = 0; r < 4; ++r) {
        obA[(size_t)(4 * g + r)      * NN] = f2bf(O0A[r]);
        obA[(size_t)(16 + 4 * g + r) * NN] = f2bf(O1A[r]);
        obB[(size_t)(4 * g + r)      * NN] = f2bf(O0B[r]);
        obB[(size_t)(16 + 4 * g + r) * NN] = f2bf(O1B[r]);
    }
    if (g == 0) {
        Lp[(size_t)part * LSEG + (size_t)bh * NN + i0 + li]      = LsA[0];
        Lp[(size_t)part * LSEG + (size_t)bh * NN + i0 + 16 + li] = LsB[0];
    }
}

// ---------------------------------------------------------------------------
// Kernel 3: output projection, 128x128-tile bf16 MFMA GEMM (R9/R11-proven
// internals).  1D grid, XCD-grouped: the 2 o-blocks sharing one (n-tile, b)
// partial-O tile are consecutive on one XCD -> partials read once from HBM.
// ---------------------------------------------------------------------------
__global__ __launch_bounds__(256) void out_proj_kernel(
    const unsigned short* __restrict__ Op, const float* __restrict__ Lp,
    const float* __restrict__ w, const float* __restrict__ bias,
    float* __restrict__ y)
{
    __shared__ unsigned short As[128 * 40];
    __shared__ unsigned short Bs[128 * 40];
    __shared__ float Linv[4][128];
    // XCD-grouped decode: Lb in [0,288)
    const int Lb   = (int)blockIdx.x;
    const int xcd  = Lb & 7;
    const int t    = Lb >> 3;            // 0..35
    const int so_  = t % 2;              // o-block varies fastest within XCD
    const int gl   = t / 2;              // 0..17
    const int group = gl * 8 + xcd;      // 0..143
    const int nb   = group % 18;
    const int b    = group / 18;
    const int n0 = nb * 128;
    const int o0 = so_ * 128;

    const int tid  = (int)threadIdx.x;
    const int wave = tid >> 6;
    const int lane = tid & 63;
    const int li   = lane & 15;
    const int g    = lane >> 4;
    const int wm = (wave & 1) * 64;
    const int wn = (wave >> 1) * 64;

    const int aco = (tid & 7) * 4;
    const int aor = tid >> 3;
    const int n4  = (tid & 31) * 4;   // B staging: n base
    const int d4  = (tid >> 5) * 4;   // B staging: d base

    {
        const int h = tid >> 6, nb2 = tid & 63;
#pragma unroll
        for (int half = 0; half < 2; ++half) {
            const int n = nb2 + 64 * half;
            float s = 0.f;
#pragma unroll
            for (int p = 0; p < PPARTS; ++p)
                s += Lp[(size_t)p * LSEG + (size_t)(b * NH + h) * NN + n0 + n];
            Linv[h][n] = 1.0f / s;
        }
    }

    f32x4 acc[4][4];
#pragma unroll
    for (int i = 0; i < 4; ++i)
#pragma unroll
        for (int j = 0; j < 4; ++j) acc[i][j] = (f32x4){0.f, 0.f, 0.f, 0.f};

    float4 wv[4];
    uint2  ov[PPARTS][4];
#pragma unroll
    for (int r = 0; r < 4; ++r)
        wv[r] = *(const float4*)&w[(size_t)(o0 + aor + 32 * r) * HIDC + aco];
    {
        const size_t bh0 = (size_t)(b * NH);
#pragma unroll
        for (int p = 0; p < PPARTS; ++p)
#pragma unroll
            for (int dd = 0; dd < 4; ++dd)
                ov[p][dd] = *(const uint2*)&Op[(size_t)p * SEG
                              + (bh0 * DH + d4 + dd) * (size_t)NN + n0 + n4];
    }

    for (int k0 = 0; k0 < HIDC; k0 += 32) {
        __syncthreads();
#pragma unroll
        for (int r = 0; r < 4; ++r) {
            uint2 pk;
            pk.x = (unsigned)f2bf(wv[r].x) | ((unsigned)f2bf(wv[r].y) << 16);
            pk.y = (unsigned)f2bf(wv[r].z) | ((unsigned)f2bf(wv[r].w) << 16);
            *(uint2*)&As[(aor + 32 * r) * 40 + aco] = pk;
        }
        const int h = k0 >> 5;                      // BK=32 == one head
        {
            float s[4][4];
#pragma unroll
            for (int dd = 0; dd < 4; ++dd)
#pragma unroll
                for (int j = 0; j < 4; ++j) s[dd][j] = 0.f;
#pragma unroll
            for (int p = 0; p < PPARTS; ++p) {
#pragma unroll
                for (int dd = 0; dd < 4; ++dd) {
                    const uint2 u = ov[p][dd];
                    s[dd][0] += bflo(u.x); s[dd][1] += bfhi(u.x);
                    s[dd][2] += bflo(u.y); s[dd][3] += bfhi(u.y);
                }
            }
#pragma unroll
            for (int j = 0; j < 4; ++j) {
                const float lv = Linv[h][n4 + j];
                uint2 pk;
                pk.x = (unsigned)f2bf(s[0][j] * lv) | ((unsigned)f2bf(s[1][j] * lv) << 16);
                pk.y = (unsigned)f2bf(s[2][j] * lv) | ((unsigned)f2bf(s[3][j] * lv) << 16);
                *(uint2*)&Bs[(n4 + j) * 40 + d4] = pk;
            }
        }
        __syncthreads();

        // prefetch next K-step (clamped on last iter; values dead)
        const int kn = (k0 + 32 < HIDC) ? (k0 + 32) : k0;
        const size_t bhn = (size_t)(b * NH + (kn >> 5));
#pragma unroll
        for (int r = 0; r < 4; ++r)
            wv[r] = *(const float4*)&w[(size_t)(o0 + aor + 32 * r) * HIDC + kn + aco];
#pragma unroll
        for (int p = 0; p < PPARTS; ++p)
#pragma unroll
            for (int dd = 0; dd < 4; ++dd)
                ov[p][dd] = *(const uint2*)&Op[(size_t)p * SEG
                              + (bhn * DH + d4 + dd) * (size_t)NN + n0 + n4];

        bf16x8 af[4], bfr[4];
#pragma unroll
        for (int mt = 0; mt < 4; ++mt)
            af[mt] = *(const bf16x8*)&As[(wm + mt * 16 + li) * 40 + g * 8];
#pragma unroll
        for (int nt = 0; nt < 4; ++nt)
            bfr[nt] = *(const bf16x8*)&Bs[(wn + nt * 16 + li) * 40 + g * 8];
#pragma unroll
        for (int mt = 0; mt < 4; ++mt)
#pragma unroll
            for (int nt = 0; nt < 4; ++nt)
                acc[mt][nt] = __builtin_amdgcn_mfma_f32_16x16x32_bf16(
                    af[mt], bfr[nt], acc[mt][nt], 0, 0, 0);
    }

#pragma unroll
    for (int mt = 0; mt < 4; ++mt) {
        const int ob = o0 + wm + mt * 16 + g * 4;
        const float b0 = bias[ob], b1 = bias[ob + 1], b2 = bias[ob + 2], b3 = bias[ob + 3];
#pragma unroll
        for (int nt = 0; nt < 4; ++nt) {
            const int n = n0 + wn + nt * 16 + li;
            const f32x4 a = acc[mt][nt];
            float* yb = y + ((size_t)(b * CDIM + ob)) * NN + n;
            yb[0]              = a[0] + b0;
            yb[(size_t)NN]     = a[1] + b1;
            yb[(size_t)2 * NN] = a[2] + b2;
            yb[(size_t)3 * NN] = a[3] + b3;
        }
    }
}

// ---------------------------------------------------------------------------
extern "C" void kernel_launch(void* const* d_in, const int* in_sizes, int n_in,
                              void* d_out, int out_size, void* d_ws, size_t ws_size,
                              hipStream_t stream)
{
    (void)in_sizes; (void)n_in; (void)out_size; (void)ws_size;
    const float* x     = (const float*)d_in[0];
    const float* w_qkv = (const float*)d_in[1];
    const float* w_out = (const float*)d_in[2];
    const float* b_out = (const float*)d_in[3];
    float* y = (float*)d_out;

    unsigned short* qt  = (unsigned short*)d_ws;
    unsigned short* kt  = qt + SEG;
    unsigned short* vtT = kt + SEG;
    unsigned short* Op  = vtT + SEG;                     // PPARTS x SEG bf16
    float* Lp = (float*)(Op + (size_t)PPARTS * SEG);     // PPARTS x LSEG fp32

    qkv_proj_kernel<<<dim3(432), 256, 0, stream>>>(x, w_qkv, qt, kt, vtT);

    attn_kernel<<<dim3(2304), 256, 0, stream>>>(qt, kt, vtT, Op, Lp);

    out_proj_kernel<<<dim3(288), 256, 0, stream>>>(Op, Lp, w_out, b_out, y);
}